// Round 6
// baseline (360.397 us; speedup 1.0000x reference)
//
#include <hip/hip_runtime.h>
#include <hip/hip_bf16.h>

// Problem constants
#define HDIM   2880
#define NH     64
#define NKV    8
#define DHEAD  64
#define GQ     (NH / NKV)     // 8
#define WIN    128
#define NTOK   1024
#define QKV_N  ((NH + 2 * NKV) * DHEAD)   // 5120
#define QCOLS  (NH * DHEAD)               // 4096
#define KOFF   QCOLS                      // 4096
#define VOFF   (QCOLS + NKV * DHEAD)      // 4608
#define WO_PAD 2944                       // 23 * 128 (pad rows stay zero)

typedef __attribute__((ext_vector_type(8))) short short8;
typedef __attribute__((ext_vector_type(4))) float floatx4;

// Static device scratch (zero-init at module load).
__device__ unsigned short g_Xb   [(size_t)NTOK  * HDIM];          //  5.9 MB
__device__ unsigned short g_qkvb [(size_t)NTOK  * QKV_N];         // 10.5 MB bf16 qkv (post-rope)
__device__ unsigned short g_attn [(size_t)NTOK  * QCOLS];         //  8.4 MB
__device__ unsigned short g_WqkvT[(size_t)QKV_N * HDIM];          // 29.5 MB
__device__ unsigned short g_WoT  [(size_t)WO_PAD * QCOLS];        // 24.1 MB (padded)

__device__ __forceinline__ unsigned short f2b(float f) {
    __hip_bfloat16 h = __float2bfloat16(f);
    return *reinterpret_cast<unsigned short*>(&h);
}

__device__ __forceinline__ void gload_lds16(const unsigned short* g, unsigned short* l) {
    __builtin_amdgcn_global_load_lds(
        (const __attribute__((address_space(1))) unsigned int*)g,
        (__attribute__((address_space(3))) unsigned int*)l, 16, 0, 0);
}

// ---------------------------------------------------------------------------
// Transpose + cvt tile body: in (K x N f32) tile (bk,bn) -> out (N x K bf16).
// ---------------------------------------------------------------------------
__device__ __forceinline__ void transpose_tile(
        const float* __restrict__ in, unsigned short* __restrict__ out,
        int K, int N, int bk, int bn, int t, unsigned short* T) {
    #pragma unroll
    for (int i = 0; i < 4; ++i) {
        int c = i * 256 + t;          // float4 slots
        int r = c >> 4, cc = (c & 15) * 4;
        float4 v = *(const float4*)(in + (size_t)(bk * 64 + r) * N + bn * 64 + cc);
        T[r * 72 + cc + 0] = f2b(v.x);
        T[r * 72 + cc + 1] = f2b(v.y);
        T[r * 72 + cc + 2] = f2b(v.z);
        T[r * 72 + cc + 3] = f2b(v.w);
    }
    __syncthreads();
    #pragma unroll
    for (int i = 0; i < 2; ++i) {
        int c = i * 256 + t;
        int rn = c >> 3, kc = (c & 7) * 8;
        int4 vv;
        unsigned short* tp = (unsigned short*)&vv;
        #pragma unroll
        for (int j = 0; j < 8; ++j) tp[j] = T[(kc + j) * 72 + rn];
        *(int4*)(out + (size_t)(bn * 64 + rn) * K + bk * 64 + kc) = vv;
    }
}

// ---------------------------------------------------------------------------
// Merged prep: Wqkv transpose (3600 blocks) + Wo transpose (2880 blocks) +
// X f32->bf16 cvt (2880 blocks). One launch instead of three.
// ---------------------------------------------------------------------------
#define NB_WQKV (45 * 80)     // 3600
#define NB_WO   (64 * 45)     // 2880
#define NB_CVT  (NTOK * HDIM / 4 / 256)   // 2880
__global__ __launch_bounds__(256) void prep(
        const float* __restrict__ X, const float* __restrict__ Wqkv,
        const float* __restrict__ Wo, unsigned short* __restrict__ Xb,
        unsigned short* __restrict__ WqkvT, unsigned short* __restrict__ WoT) {
    __shared__ __align__(16) unsigned short T[64 * 72];
    int id = blockIdx.x;
    int t = threadIdx.x;
    if (id < NB_WQKV) {
        transpose_tile(Wqkv, WqkvT, HDIM, QKV_N, id % 45, id / 45, t, T);
    } else if (id < NB_WQKV + NB_WO) {
        int id2 = id - NB_WQKV;
        transpose_tile(Wo, WoT, QCOLS, HDIM, id2 % 64, id2 / 64, t, T);
    } else {
        int gid = (id - NB_WQKV - NB_WO) * 256 + t;
        float4 v = *(const float4*)(X + (size_t)gid * 4);
        ushort4 o;
        o.x = f2b(v.x); o.y = f2b(v.y); o.z = f2b(v.z); o.w = f2b(v.w);
        *(ushort4*)(Xb + (size_t)gid * 4) = o;
    }
}

// ---------------------------------------------------------------------------
// Direct full-K GEMM, 128x128 tile (m97-proven shape), BK=64, 4 waves 2x2,
// each wave 64x64 (acc 4x4 of 16x16 frags).  Round-2 schedule (proven):
// 2-phase double-buffered, STAGE(next) issued before compute(cur), one
// __syncthreads per K-step.  Doubling per-step MFMA/ds_read work amortizes
// the per-step staging drain (the measured per-step latency cost) over 2x
// the FLOPs vs the 128x64 tile.
// LDS XOR-swizzle via inverse-permuted global source (global_load_lds dest
// stays linear) + permuted ds_read address.
// XCD-aware bijective block swizzle (grid = 8*NBN, NBN col-tiles of 128).
// MODE 0: fused RoPE epilogue -> bf16 qkv (each wave's 64-col half == one
//         head: hh = bn*2 + wn).
// MODE 1: plain f32 store to out (ld HDIM), guarded for the N=2944 pad.
// ---------------------------------------------------------------------------
template<int KLEN, int MODE, int NBN>
__global__ __launch_bounds__(256) void gemm_dir(
        const unsigned short* __restrict__ A, const unsigned short* __restrict__ Bt,
        void* __restrict__ outp) {
    int d0 = blockIdx.x;                       // nwg = 8*NBN, nwg % 8 == 0
    int work = (d0 & 7) * NBN + (d0 >> 3);     // bijective XCD chunking
    int bm = work & 7, bn = work >> 3;         // 8 row tiles x NBN col tiles
    int t = threadIdx.x, lane = t & 63, wid = t >> 6;
    int quad = lane >> 4, ml = lane & 15;
    int wm = wid >> 1, wn = wid & 1;
    __shared__ __align__(16) unsigned short As[2][128 * 64];   // 2 x 16 KB
    __shared__ __align__(16) unsigned short Bs[2][128 * 64];   // 2 x 16 KB
    floatx4 acc[4][4];
    #pragma unroll
    for (int i = 0; i < 4; ++i)
        #pragma unroll
        for (int j = 0; j < 4; ++j) acc[i][j] = (floatx4){0.f, 0.f, 0.f, 0.f};

    int srow = lane >> 3;                      // 0..7 within an 8-row group
    int scol = ((lane & 7) ^ srow) * 8;        // inverse-swizzled source unit
    const unsigned short* Ab = A  + (size_t)(bm * 128) * KLEN;
    const unsigned short* Bb = Bt + (size_t)(bn * 128) * KLEN;

    constexpr int NT = KLEN / 64;

    // prologue: stage tile 0 into buffer 0 (A: 16 groups, B: 16 groups)
    #pragma unroll
    for (int j = 0; j < 4; ++j) {
        int grp = wid * 4 + j;
        int r = grp * 8 + srow;
        gload_lds16(Ab + (size_t)r * KLEN + scol, &As[0][grp * 512]);
        gload_lds16(Bb + (size_t)r * KLEN + scol, &Bs[0][grp * 512]);
    }
    __syncthreads();

    for (int ti = 0; ti < NT; ++ti) {
        int cur = ti & 1;
        if (ti + 1 < NT) {                     // issue next-tile loads first
            int k0 = (ti + 1) * 64;
            int nxt = cur ^ 1;
            #pragma unroll
            for (int j = 0; j < 4; ++j) {
                int grp = wid * 4 + j;
                int r = grp * 8 + srow;
                gload_lds16(Ab + (size_t)r * KLEN + k0 + scol, &As[nxt][grp * 512]);
                gload_lds16(Bb + (size_t)r * KLEN + k0 + scol, &Bs[nxt][grp * 512]);
            }
        }
        #pragma unroll
        for (int kk = 0; kk < 64; kk += 32) {
            const int ub = kk >> 3;            // 0 or 4
            int usw = ((ub + quad) ^ (ml & 7)) * 8;
            short8 af[4], bf[4];
            #pragma unroll
            for (int mt = 0; mt < 4; ++mt)
                af[mt] = *(const short8*)&As[cur][(wm * 64 + mt * 16 + ml) * 64 + usw];
            #pragma unroll
            for (int nt = 0; nt < 4; ++nt)
                bf[nt] = *(const short8*)&Bs[cur][(wn * 64 + nt * 16 + ml) * 64 + usw];
            #pragma unroll
            for (int mt = 0; mt < 4; ++mt)
                #pragma unroll
                for (int nt = 0; nt < 4; ++nt)
                    acc[mt][nt] = __builtin_amdgcn_mfma_f32_16x16x32_bf16(af[mt], bf[nt], acc[mt][nt], 0, 0, 0);
        }
        __syncthreads();   // drains this wave's vmcnt (next tile staged) + read fence
    }

    if constexpr (MODE == 0) {
        // wave's 64-col half == head hh; heads 0..71 q/k (RoPE), 72..79 v.
        unsigned short* qp = (unsigned short*)outp;
        int hh = bn * 2 + wn;
        int cb = bn * 128 + wn * 64;
        if (hh < NH + NKV) {
            // inv_freq for this lane's two d values (d = ml, d = 16+ml)
            float inv0 = expf(-(float)ml * 0.3724497053f);          // theta^(-d/32)
            float inv1 = expf(-(float)(16 + ml) * 0.3724497053f);
            #pragma unroll
            for (int mt = 0; mt < 4; ++mt) {
                #pragma unroll
                for (int r = 0; r < 4; ++r) {
                    int n = bm * 128 + wm * 64 + mt * 16 + quad * 4 + r;
                    unsigned short* op = qp + (size_t)n * QKV_N + cb;
                    float s0, c0, s1, c1;
                    sincosf((float)n * inv0, &s0, &c0);
                    sincosf((float)n * inv1, &s1, &c1);
                    float x1a = acc[mt][0][r], x2a = acc[mt][2][r];
                    float x1b = acc[mt][1][r], x2b = acc[mt][3][r];
                    op[ml]           = f2b(x1a * c0 - x2a * s0);
                    op[ml + 32]      = f2b(x2a * c0 + x1a * s0);
                    op[16 + ml]      = f2b(x1b * c1 - x2b * s1);
                    op[16 + ml + 32] = f2b(x2b * c1 + x1b * s1);
                }
            }
        } else {
            #pragma unroll
            for (int mt = 0; mt < 4; ++mt)
                #pragma unroll
                for (int r = 0; r < 4; ++r) {
                    int n = bm * 128 + wm * 64 + mt * 16 + quad * 4 + r;
                    unsigned short* op = qp + (size_t)n * QKV_N + cb;
                    #pragma unroll
                    for (int nt = 0; nt < 4; ++nt)
                        op[nt * 16 + ml] = f2b(acc[mt][nt][r]);
                }
        }
    } else {
        float* op0 = (float*)outp;
        int cb = bn * 128 + wn * 64;
        if (cb < HDIM) {                       // pad guard (bn=22, wn=1 skipped)
            #pragma unroll
            for (int mt = 0; mt < 4; ++mt)
                #pragma unroll
                for (int r = 0; r < 4; ++r) {
                    int n = bm * 128 + wm * 64 + mt * 16 + quad * 4 + r;
                    float* op = op0 + (size_t)n * HDIM + cb;
                    #pragma unroll
                    for (int nt = 0; nt < 4; ++nt)
                        op[nt * 16 + ml] = acc[mt][nt][r];
                }
        }
    }
}

// ---------------------------------------------------------------------------
// MFMA flash-style sliding-window attention with sinks, bf16 in/out.
// 1D grid 512 with XCD swizzle: each XCD owns one kv-head (K/V L2-resident).
// Block = (16-token Q-tile, kv-head); M = 8 heads x 16 tokens = 128 rows;
// wave w owns rows [w*32, w*32+32). Window rows [t0-127, t0+32].
// K is NOT LDS-staged (per-XCD K-slice is 128 KB, L2-resident); QK^T
// B-fragments are per-lane 16-B gathers from L2. Only V (transposed) + Ps
// use LDS -> 42 KB, 3 blocks/CU.
// ---------------------------------------------------------------------------
#define TQ     16
#define VT_LD  168
#define PS_LD  168

__global__ __launch_bounds__(256) void attn_mfma(
        const unsigned short* __restrict__ qkvb,
        const float* __restrict__ sinks,
        unsigned short* __restrict__ aout) {
    int d0 = blockIdx.x;                       // 512 blocks
    int work = (d0 & 7) * 64 + (d0 >> 3);      // bijective: XCD x -> kh == x
    int t0 = (work & 63) * TQ, kh = work >> 6;
    int t = threadIdx.x, lane = t & 63, wid = t >> 6;
    int quad = lane >> 4, ml = lane & 15;
    int wavebase = wid * 32;

    __shared__ __align__(16) unsigned short Vt[DHEAD * VT_LD];    // 21 KB
    __shared__ __align__(16) unsigned short Ps[4 * 16 * PS_LD];   // 21 KB
    unsigned short* Psw = &Ps[wid * 16 * PS_LD];

    // ---- stage V only (transposed), straight bf16 copies
    #pragma unroll
    for (int i = 0; i < 5; ++i) {
        int c = i * 256 + t;              // 0..1279 ushort8 slots
        int w = c >> 3, d8 = (c & 7) * 8;
        int r = t0 - 127 + w;
        r = min(max(r, 0), NTOK - 1);
        int4 vv = *(const int4*)(qkvb + (size_t)r * QKV_N + VOFF + kh * DHEAD + d8);
        const unsigned short* vp = (const unsigned short*)&vv;
        #pragma unroll
        for (int j = 0; j < 8; ++j) Vt[(d8 + j) * VT_LD + w] = vp[j];
    }
    __syncthreads();

    // ---- Q A-fragments straight from global bf16
    short8 qf[2][2];
    #pragma unroll
    for (int mt = 0; mt < 2; ++mt) {
        int m = wavebase + mt * 16 + ml;
        int tl = m & 15, g = m >> 4;
        const unsigned short* qp = qkvb + (size_t)(t0 + tl) * QKV_N + (kh * GQ + g) * DHEAD;
        #pragma unroll
        for (int kk = 0; kk < 2; ++kk)
            qf[mt][kk] = *(const short8*)(qp + kk * 32 + quad * 8);
    }

    // ---- S = Q K^T, K fragments gathered from global (L2-hit)
    const unsigned short* Kbase = qkvb + KOFF + kh * DHEAD;
    floatx4 S[2][10];
    #pragma unroll
    for (int mt = 0; mt < 2; ++mt)
        #pragma unroll
        for (int nt = 0; nt < 10; ++nt) S[mt][nt] = (floatx4){0.f, 0.f, 0.f, 0.f};
    #pragma unroll
    for (int kk = 0; kk < 2; ++kk) {
        #pragma unroll
        for (int nt = 0; nt < 10; ++nt) {
            int r = t0 - 127 + nt * 16 + ml;
            r = min(max(r, 0), NTOK - 1);
            short8 kb = *(const short8*)(Kbase + (size_t)r * QKV_N + kk * 32 + quad * 8);
            #pragma unroll
            for (int mt = 0; mt < 2; ++mt)
                S[mt][nt] = __builtin_amdgcn_mfma_f32_16x16x32_bf16(qf[mt][kk], kb, S[mt][nt], 0, 0, 0);
        }
    }

    // ---- band mask + scale   (valid: w>=tl, w<=tl+127, w>=127-t0)
    int wmin0 = 127 - t0;
    #pragma unroll
    for (int mt = 0; mt < 2; ++mt) {
        #pragma unroll
        for (int r = 0; r < 4; ++r) {
            int tl = (wavebase + mt * 16 + quad * 4 + r) & 15;
            int wlo = tl > wmin0 ? tl : wmin0;
            int whi = tl + 127;
            #pragma unroll
            for (int nt = 0; nt < 10; ++nt) {
                int w = nt * 16 + ml;
                float s = S[mt][nt][r] * 0.125f;
                S[mt][nt][r] = (w >= wlo && w <= whi) ? s : -INFINITY;
            }
        }
    }

    // ---- softmax with sink (rows spread over 16 lanes of the quad)
    #pragma unroll
    for (int mt = 0; mt < 2; ++mt) {
        int g = (wavebase + mt * 16) >> 4;
        float sk = sinks[kh * GQ + g];
        #pragma unroll
        for (int r = 0; r < 4; ++r) {
            float rm = -INFINITY;
            #pragma unroll
            for (int nt = 0; nt < 10; ++nt) rm = fmaxf(rm, S[mt][nt][r]);
            #pragma unroll
            for (int off = 1; off < 16; off <<= 1) rm = fmaxf(rm, __shfl_xor(rm, off));
            rm = fmaxf(rm, sk);
            float sum = 0.f;
            #pragma unroll
            for (int nt = 0; nt < 10; ++nt) {
                float p = __expf(S[mt][nt][r] - rm);   // exp(-inf)=0 masks
                S[mt][nt][r] = p;
                sum += p;
            }
            #pragma unroll
            for (int off = 1; off < 16; off <<= 1) sum += __shfl_xor(sum, off);
            float inv = 1.f / (sum + __expf(sk - rm));
            #pragma unroll
            for (int nt = 0; nt < 10; ++nt) S[mt][nt][r] *= inv;
        }
    }

    // ---- PV one m-tile at a time through per-wave Ps (wave DS ops in-order)
    #pragma unroll
    for (int mt = 0; mt < 2; ++mt) {
        #pragma unroll
        for (int r = 0; r < 4; ++r) {
            int lr = quad * 4 + r;
            #pragma unroll
            for (int nt = 0; nt < 10; ++nt)
                Psw[lr * PS_LD + nt * 16 + ml] = f2b(S[mt][nt][r]);
        }
        floatx4 O[4];
        #pragma unroll
        for (int j = 0; j < 4; ++j) O[j] = (floatx4){0.f, 0.f, 0.f, 0.f};
        #pragma unroll
        for (int ks = 0; ks < 5; ++ks) {
            short8 pf = *(const short8*)&Psw[ml * PS_LD + ks * 32 + quad * 8];
            #pragma unroll
            for (int nt = 0; nt < 4; ++nt) {
                short8 vf = *(const short8*)&Vt[(nt * 16 + ml) * VT_LD + ks * 32 + quad * 8];
                O[nt] = __builtin_amdgcn_mfma_f32_16x16x32_bf16(pf, vf, O[nt], 0, 0, 0);
            }
        }
        #pragma unroll
        for (int r = 0; r < 4; ++r) {
            int mm = wavebase + mt * 16 + quad * 4 + r;
            int tl = mm & 15, g = mm >> 4;
            unsigned short* op = aout + (size_t)(t0 + tl) * QCOLS + (kh * GQ + g) * DHEAD;
            #pragma unroll
            for (int nt = 0; nt < 4; ++nt)
                op[nt * 16 + ml] = f2b(O[nt][r]);
        }
    }
}

// ---------------------------------------------------------------------------
extern "C" void kernel_launch(void* const* d_in, const int* in_sizes, int n_in,
                              void* d_out, int out_size, void* d_ws, size_t ws_size,
                              hipStream_t stream) {
    const float* X     = (const float*)d_in[0];  // 1024x2880 f32
    const float* Wqkv  = (const float*)d_in[1];  // 2880x5120 f32
    const float* Wo    = (const float*)d_in[2];  // 4096x2880 f32
    const float* sinks = (const float*)d_in[3];  // 64 f32
    float* out = (float*)d_out;                  // 1024x2880 f32

    unsigned short *Xb, *qkvb, *attn, *WqkvT, *WoT;
    hipGetSymbolAddress((void**)&Xb,    HIP_SYMBOL(g_Xb));
    hipGetSymbolAddress((void**)&qkvb,  HIP_SYMBOL(g_qkvb));
    hipGetSymbolAddress((void**)&attn,  HIP_SYMBOL(g_attn));
    hipGetSymbolAddress((void**)&WqkvT, HIP_SYMBOL(g_WqkvT));
    hipGetSymbolAddress((void**)&WoT,   HIP_SYMBOL(g_WoT));

    // Merged cvt + both weight transposes (one launch)
    prep<<<NB_WQKV + NB_WO + NB_CVT, 256, 0, stream>>>(X, Wqkv, Wo, Xb, WqkvT, WoT);

    // QKV projection, 128x128 tiles, fused RoPE -> bf16 qkv (320 blocks)
    gemm_dir<HDIM, 0, QKV_N / 128><<<8 * (QKV_N / 128), 256, 0, stream>>>(Xb, WqkvT, qkvb);

    // MFMA sliding-window attention -> bf16 attn
    attn_mfma<<<512, 256, 0, stream>>>(qkvb, sinks, attn);

    // Output projection, 128x128 tiles (padded N=2944) -> f32 out (184 blocks)
    gemm_dir<QCOLS, 1, WO_PAD / 128><<<8 * (WO_PAD / 128), 256, 0, stream>>>(attn, WoT, out);
}

// Round 8
// 341.101 us; speedup vs baseline: 1.0566x; 1.0566x over previous
//
#include <hip/hip_runtime.h>
#include <hip/hip_bf16.h>

// Problem constants
#define HDIM   2880
#define NH     64
#define NKV    8
#define DHEAD  64
#define GQ     (NH / NKV)     // 8
#define WIN    128
#define NTOK   1024
#define QKV_N  ((NH + 2 * NKV) * DHEAD)   // 5120
#define QCOLS  (NH * DHEAD)               // 4096
#define KOFF   QCOLS                      // 4096
#define VOFF   (QCOLS + NKV * DHEAD)      // 4608
#define VT_STRIDE 1280                    // 128-token guard each side

typedef __attribute__((ext_vector_type(8))) short short8;
typedef __attribute__((ext_vector_type(4))) float floatx4;

// Static device scratch (zero-init at module load).
__device__ unsigned short g_Xb   [(size_t)NTOK  * HDIM];          //  5.9 MB
__device__ unsigned short g_qkvb [(size_t)NTOK  * QKV_N];         // 10.5 MB bf16 qkv (post-rope)
__device__ unsigned short g_attn [(size_t)NTOK  * QCOLS];         //  8.4 MB
__device__ unsigned short g_vT   [(size_t)(NKV * DHEAD) * VT_STRIDE]; // 1.3 MB transposed V
__device__ unsigned short g_WqkvT[(size_t)QKV_N * HDIM];          // 29.5 MB
__device__ unsigned short g_WoT  [(size_t)HDIM * QCOLS];          // 23.6 MB

__device__ __forceinline__ unsigned short f2b(float f) {
    __hip_bfloat16 h = __float2bfloat16(f);
    return *reinterpret_cast<unsigned short*>(&h);
}

__device__ __forceinline__ void gload_lds16(const unsigned short* g, unsigned short* l) {
    __builtin_amdgcn_global_load_lds(
        (const __attribute__((address_space(1))) unsigned int*)g,
        (__attribute__((address_space(3))) unsigned int*)l, 16, 0, 0);
}

// ---------------------------------------------------------------------------
// Transpose + cvt tile body: in (K x N f32) tile (bk,bn) -> out (N x K bf16).
// ---------------------------------------------------------------------------
__device__ __forceinline__ void transpose_tile(
        const float* __restrict__ in, unsigned short* __restrict__ out,
        int K, int N, int bk, int bn, int t, unsigned short* T) {
    #pragma unroll
    for (int i = 0; i < 4; ++i) {
        int c = i * 256 + t;          // float4 slots
        int r = c >> 4, cc = (c & 15) * 4;
        float4 v = *(const float4*)(in + (size_t)(bk * 64 + r) * N + bn * 64 + cc);
        T[r * 72 + cc + 0] = f2b(v.x);
        T[r * 72 + cc + 1] = f2b(v.y);
        T[r * 72 + cc + 2] = f2b(v.z);
        T[r * 72 + cc + 3] = f2b(v.w);
    }
    __syncthreads();
    #pragma unroll
    for (int i = 0; i < 2; ++i) {
        int c = i * 256 + t;
        int rn = c >> 3, kc = (c & 7) * 8;
        int4 vv;
        unsigned short* tp = (unsigned short*)&vv;
        #pragma unroll
        for (int j = 0; j < 8; ++j) tp[j] = T[(kc + j) * 72 + rn];
        *(int4*)(out + (size_t)(bn * 64 + rn) * K + bk * 64 + kc) = vv;
    }
}

// ---------------------------------------------------------------------------
// Merged prep: Wqkv transpose + Wo transpose + X f32->bf16 cvt.
// ---------------------------------------------------------------------------
#define NB_WQKV (45 * 80)     // 3600
#define NB_WO   (64 * 45)     // 2880
#define NB_CVT  (NTOK * HDIM / 4 / 256)   // 2880
__global__ __launch_bounds__(256) void prep(
        const float* __restrict__ X, const float* __restrict__ Wqkv,
        const float* __restrict__ Wo, unsigned short* __restrict__ Xb,
        unsigned short* __restrict__ WqkvT, unsigned short* __restrict__ WoT) {
    __shared__ __align__(16) unsigned short T[64 * 72];
    int id = blockIdx.x;
    int t = threadIdx.x;
    if (id < NB_WQKV) {
        transpose_tile(Wqkv, WqkvT, HDIM, QKV_N, id % 45, id / 45, t, T);
    } else if (id < NB_WQKV + NB_WO) {
        int id2 = id - NB_WQKV;
        transpose_tile(Wo, WoT, QCOLS, HDIM, id2 % 64, id2 / 64, t, T);
    } else {
        int gid = (id - NB_WQKV - NB_WO) * 256 + t;
        float4 v = *(const float4*)(X + (size_t)gid * 4);
        ushort4 o;
        o.x = f2b(v.x); o.y = f2b(v.y); o.z = f2b(v.z); o.w = f2b(v.w);
        *(ushort4*)(Xb + (size_t)gid * 4) = o;
    }
}

// ---------------------------------------------------------------------------
// Direct full-K GEMM, 128x64 tile, BK=64, 4 waves stacked in M (each wave
// 32 rows x 64 cols, acc 2x4 of 16x16 frags).  [round-2 schedule: proven]
// 2-phase double-buffered: STAGE(next) issued before compute(cur); one
// __syncthreads per K-step. LDS XOR-swizzle via inverse-permuted global
// source (global_load_lds dest stays linear) + permuted ds_read address.
// XCD-aware bijective block swizzle (grid = 8*NBN, NBN col-tiles of 64).
// MODE 0: col tile bn == one head. Heads 0..71 (q/k): fused RoPE -> bf16
//         qkv. Heads 72..79 (v): write TRANSPOSED into vT (guarded layout)
//         so attention needs no LDS V-transpose.
// MODE 1: plain f32 store to out (ld HDIM).
// ---------------------------------------------------------------------------
template<int KLEN, int MODE, int NBN>
__global__ __launch_bounds__(256) void gemm_dir(
        const unsigned short* __restrict__ A, const unsigned short* __restrict__ Bt,
        void* __restrict__ outp, unsigned short* __restrict__ vTp) {
    int d0 = blockIdx.x;                       // nwg = 8*NBN, nwg % 8 == 0
    int work = (d0 & 7) * NBN + (d0 >> 3);     // bijective XCD chunking
    int bm = work & 7, bn = work >> 3;         // 8 row tiles x NBN col tiles
    int t = threadIdx.x, lane = t & 63, wid = t >> 6;
    int quad = lane >> 4, ml = lane & 15;
    __shared__ __align__(16) unsigned short As[2][128 * 64];   // 2 x 16 KB
    __shared__ __align__(16) unsigned short Bs[2][64 * 64];    // 2 x  8 KB
    floatx4 acc[2][4];
    #pragma unroll
    for (int i = 0; i < 2; ++i)
        #pragma unroll
        for (int j = 0; j < 4; ++j) acc[i][j] = (floatx4){0.f, 0.f, 0.f, 0.f};

    int srow = lane >> 3;                      // 0..7 within an 8-row group
    int scol = ((lane & 7) ^ srow) * 8;        // inverse-swizzled source unit
    const unsigned short* Ab = A  + (size_t)(bm * 128) * KLEN;
    const unsigned short* Bb = Bt + (size_t)(bn * 64) * KLEN;

    constexpr int NT = KLEN / 64;

    // prologue: stage tile 0 into buffer 0
    #pragma unroll
    for (int j = 0; j < 4; ++j) {
        int grp = wid * 4 + j;
        int r = grp * 8 + srow;
        gload_lds16(Ab + (size_t)r * KLEN + scol, &As[0][grp * 512]);
    }
    #pragma unroll
    for (int j = 0; j < 2; ++j) {
        int grp = wid * 2 + j;
        int r = grp * 8 + srow;
        gload_lds16(Bb + (size_t)r * KLEN + scol, &Bs[0][grp * 512]);
    }
    __syncthreads();

    for (int ti = 0; ti < NT; ++ti) {
        int cur = ti & 1;
        if (ti + 1 < NT) {                     // issue next-tile loads first
            int k0 = (ti + 1) * 64;
            int nxt = cur ^ 1;
            #pragma unroll
            for (int j = 0; j < 4; ++j) {
                int grp = wid * 4 + j;
                int r = grp * 8 + srow;
                gload_lds16(Ab + (size_t)r * KLEN + k0 + scol, &As[nxt][grp * 512]);
            }
            #pragma unroll
            for (int j = 0; j < 2; ++j) {
                int grp = wid * 2 + j;
                int r = grp * 8 + srow;
                gload_lds16(Bb + (size_t)r * KLEN + k0 + scol, &Bs[nxt][grp * 512]);
            }
        }
        #pragma unroll
        for (int kk = 0; kk < 64; kk += 32) {
            const int ub = kk >> 3;            // 0 or 4
            int usw = ((ub + quad) ^ (ml & 7)) * 8;
            short8 af[2], bf[4];
            #pragma unroll
            for (int mt = 0; mt < 2; ++mt)
                af[mt] = *(const short8*)&As[cur][(wid * 32 + mt * 16 + ml) * 64 + usw];
            #pragma unroll
            for (int nt = 0; nt < 4; ++nt)
                bf[nt] = *(const short8*)&Bs[cur][(nt * 16 + ml) * 64 + usw];
            #pragma unroll
            for (int mt = 0; mt < 2; ++mt)
                #pragma unroll
                for (int nt = 0; nt < 4; ++nt)
                    acc[mt][nt] = __builtin_amdgcn_mfma_f32_16x16x32_bf16(af[mt], bf[nt], acc[mt][nt], 0, 0, 0);
        }
        __syncthreads();   // drains this wave's vmcnt (next tile staged) + read fence
    }

    if constexpr (MODE == 0) {
        // col tile bn == head bn; heads 0..71 are q/k (RoPE), 72..79 are v.
        unsigned short* qp = (unsigned short*)outp;
        int cb = bn * 64;
        if (bn < NH + NKV) {
            // inv_freq for this lane's two d values (d = ml, d = 16+ml)
            float inv0 = expf(-(float)ml * 0.3724497053f);          // theta^(-d/32)
            float inv1 = expf(-(float)(16 + ml) * 0.3724497053f);
            #pragma unroll
            for (int mt = 0; mt < 2; ++mt) {
                #pragma unroll
                for (int r = 0; r < 4; ++r) {
                    int n = bm * 128 + wid * 32 + mt * 16 + quad * 4 + r;
                    unsigned short* op = qp + (size_t)n * QKV_N + cb;
                    float s0, c0, s1, c1;
                    sincosf((float)n * inv0, &s0, &c0);
                    sincosf((float)n * inv1, &s1, &c1);
                    float x1a = acc[mt][0][r], x2a = acc[mt][2][r];
                    float x1b = acc[mt][1][r], x2b = acc[mt][3][r];
                    op[ml]           = f2b(x1a * c0 - x2a * s0);
                    op[ml + 32]      = f2b(x2a * c0 + x1a * s0);
                    op[16 + ml]      = f2b(x1b * c1 - x2b * s1);
                    op[16 + ml + 32] = f2b(x2b * c1 + x1b * s1);
                }
            }
        } else {
            // v-head: scatter transposed into vT (row = kvh*64+d, guarded tokens)
            unsigned short* vp = vTp + (size_t)((bn - NH - NKV) * 64) * VT_STRIDE + 128;
            #pragma unroll
            for (int mt = 0; mt < 2; ++mt)
                #pragma unroll
                for (int r = 0; r < 4; ++r) {
                    int n = bm * 128 + wid * 32 + mt * 16 + quad * 4 + r;
                    #pragma unroll
                    for (int nt = 0; nt < 4; ++nt)
                        vp[(size_t)(nt * 16 + ml) * VT_STRIDE + n] = f2b(acc[mt][nt][r]);
                }
        }
    } else {
        float* op0 = (float*)outp;
        #pragma unroll
        for (int mt = 0; mt < 2; ++mt)
            #pragma unroll
            for (int r = 0; r < 4; ++r) {
                int n = bm * 128 + wid * 32 + mt * 16 + quad * 4 + r;
                float* op = op0 + (size_t)n * HDIM + bn * 64;
                #pragma unroll
                for (int nt = 0; nt < 4; ++nt)
                    op[nt * 16 + ml] = acc[mt][nt][r];
            }
    }
}

// ---------------------------------------------------------------------------
// MFMA sliding-window attention with sinks — barrier-free, gather-based.
// Grid 1024 (XCD-major swizzle: each XCD owns one kv-head). Block = 4
// independent waves; wave = (16-token Q-tile, one q-head): QK^T via
// line-efficient K gathers from L2, softmax in-register, PV via pre-
// transposed vT gathers from L2. LDS = per-wave Ps only (21 KB), no
// __syncthreads anywhere -> deep wave-level latency hiding.
// ---------------------------------------------------------------------------
#define TQ     16
#define PS_LD  168

__global__ __launch_bounds__(256) void attn_mfma(
        const unsigned short* __restrict__ qkvb,
        const unsigned short* __restrict__ vT,
        const float* __restrict__ sinks,
        unsigned short* __restrict__ aout) {
    int d0 = blockIdx.x;                       // 1024 blocks
    int work = (d0 & 7) * 128 + (d0 >> 3);     // bijective: kh == XCD
    int kh = work >> 7;
    int rem = work & 127;
    int t0 = (rem >> 1) * TQ;
    int half = rem & 1;
    int t = threadIdx.x, lane = t & 63, wid = t >> 6;
    int quad = lane >> 4, ml = lane & 15;
    int g = half * 4 + wid;                    // q-head within kv group

    __shared__ __align__(16) unsigned short Ps[4 * 16 * PS_LD];   // 21 KB
    unsigned short* Psw = &Ps[wid * 16 * PS_LD];

    // ---- Q A-fragments (token = ml)
    const unsigned short* qp = qkvb + (size_t)(t0 + ml) * QKV_N + (kh * GQ + g) * DHEAD;
    short8 qf0 = *(const short8*)(qp + quad * 8);
    short8 qf1 = *(const short8*)(qp + 32 + quad * 8);

    // ---- S = Q K^T, K gathered from L2 (16 rows x 64B per instr)
    const unsigned short* Kbase = qkvb + KOFF + kh * DHEAD;
    floatx4 S[10];
    #pragma unroll
    for (int nt = 0; nt < 10; ++nt) S[nt] = (floatx4){0.f, 0.f, 0.f, 0.f};
    #pragma unroll
    for (int nt = 0; nt < 10; ++nt) {
        int r = t0 - 127 + nt * 16 + ml;
        r = min(max(r, 0), NTOK - 1);
        const unsigned short* kp = Kbase + (size_t)r * QKV_N;
        short8 kb0 = *(const short8*)(kp + quad * 8);
        short8 kb1 = *(const short8*)(kp + 32 + quad * 8);
        S[nt] = __builtin_amdgcn_mfma_f32_16x16x32_bf16(qf0, kb0, S[nt], 0, 0, 0);
        S[nt] = __builtin_amdgcn_mfma_f32_16x16x32_bf16(qf1, kb1, S[nt], 0, 0, 0);
    }

    // ---- band mask + scale (token row = quad*4+r, w col = nt*16+ml)
    int wmin0 = 127 - t0;
    #pragma unroll
    for (int r = 0; r < 4; ++r) {
        int tl = quad * 4 + r;
        int wlo = tl > wmin0 ? tl : wmin0;
        int whi = tl + 127;
        #pragma unroll
        for (int nt = 0; nt < 10; ++nt) {
            int w = nt * 16 + ml;
            float s = S[nt][r] * 0.125f;
            S[nt][r] = (w >= wlo && w <= whi) ? s : -INFINITY;
        }
    }

    // ---- softmax with sink (row spread over 16 lanes of the quad)
    float sk = sinks[kh * GQ + g];
    #pragma unroll
    for (int r = 0; r < 4; ++r) {
        float rm = -INFINITY;
        #pragma unroll
        for (int nt = 0; nt < 10; ++nt) rm = fmaxf(rm, S[nt][r]);
        #pragma unroll
        for (int off = 1; off < 16; off <<= 1) rm = fmaxf(rm, __shfl_xor(rm, off));
        rm = fmaxf(rm, sk);
        float sum = 0.f;
        #pragma unroll
        for (int nt = 0; nt < 10; ++nt) {
            float p = __expf(S[nt][r] - rm);   // exp(-inf)=0 masks
            S[nt][r] = p;
            sum += p;
        }
        #pragma unroll
        for (int off = 1; off < 16; off <<= 1) sum += __shfl_xor(sum, off);
        float inv = 1.f / (sum + __expf(sk - rm));
        #pragma unroll
        for (int nt = 0; nt < 10; ++nt) S[nt][r] *= inv;
    }

    // ---- P -> bf16 via per-wave Ps (wave-local DS, in-order, no barrier)
    #pragma unroll
    for (int r = 0; r < 4; ++r) {
        int lr = quad * 4 + r;
        #pragma unroll
        for (int nt = 0; nt < 10; ++nt)
            Psw[lr * PS_LD + nt * 16 + ml] = f2b(S[nt][r]);
    }

    // ---- PV: V gathered from pre-transposed vT (16 rows x 64B per instr)
    const unsigned short* Vb = vT + (size_t)(kh * 64) * VT_STRIDE + 128 + t0 - 127;
    floatx4 O[4];
    #pragma unroll
    for (int j = 0; j < 4; ++j) O[j] = (floatx4){0.f, 0.f, 0.f, 0.f};
    #pragma unroll
    for (int ks = 0; ks < 5; ++ks) {
        short8 pf = *(const short8*)&Psw[ml * PS_LD + ks * 32 + quad * 8];
        #pragma unroll
        for (int nt = 0; nt < 4; ++nt) {
            short8 vf = *(const short8*)(Vb + (size_t)(nt * 16 + ml) * VT_STRIDE + ks * 32 + quad * 8);
            O[nt] = __builtin_amdgcn_mfma_f32_16x16x32_bf16(pf, vf, O[nt], 0, 0, 0);
        }
    }

    // ---- write O (row = quad*4+r, col d = nt*16+ml)
    #pragma unroll
    for (int r = 0; r < 4; ++r) {
        int tok = t0 + quad * 4 + r;
        unsigned short* op = aout + (size_t)tok * QCOLS + (kh * GQ + g) * DHEAD;
        #pragma unroll
        for (int nt = 0; nt < 4; ++nt)
            op[nt * 16 + ml] = f2b(O[nt][r]);
    }
}

// ---------------------------------------------------------------------------
extern "C" void kernel_launch(void* const* d_in, const int* in_sizes, int n_in,
                              void* d_out, int out_size, void* d_ws, size_t ws_size,
                              hipStream_t stream) {
    const float* X     = (const float*)d_in[0];  // 1024x2880 f32
    const float* Wqkv  = (const float*)d_in[1];  // 2880x5120 f32
    const float* Wo    = (const float*)d_in[2];  // 4096x2880 f32
    const float* sinks = (const float*)d_in[3];  // 64 f32
    float* out = (float*)d_out;                  // 1024x2880 f32

    unsigned short *Xb, *qkvb, *attn, *vT, *WqkvT, *WoT;
    hipGetSymbolAddress((void**)&Xb,    HIP_SYMBOL(g_Xb));
    hipGetSymbolAddress((void**)&qkvb,  HIP_SYMBOL(g_qkvb));
    hipGetSymbolAddress((void**)&attn,  HIP_SYMBOL(g_attn));
    hipGetSymbolAddress((void**)&vT,    HIP_SYMBOL(g_vT));
    hipGetSymbolAddress((void**)&WqkvT, HIP_SYMBOL(g_WqkvT));
    hipGetSymbolAddress((void**)&WoT,   HIP_SYMBOL(g_WoT));

    // Merged cvt + both weight transposes (one launch)
    prep<<<NB_WQKV + NB_WO + NB_CVT, 256, 0, stream>>>(X, Wqkv, Wo, Xb, WqkvT, WoT);

    // QKV projection, fused RoPE + transposed-V epilogue (640 blocks)
    gemm_dir<HDIM, 0, QKV_N / 64><<<8 * (QKV_N / 64), 256, 0, stream>>>(Xb, WqkvT, qkvb, vT);

    // Barrier-free MFMA sliding-window attention -> bf16 attn (1024 blocks)
    attn_mfma<<<1024, 256, 0, stream>>>(qkvb, vT, sinks, attn);

    // Output projection -> f32 out (360 blocks)
    gemm_dir<QCOLS, 1, HDIM / 64><<<8 * (HDIM / 64), 256, 0, stream>>>(attn, WoT, out, nullptr);
}

// Round 9
// 327.544 us; speedup vs baseline: 1.1003x; 1.0414x over previous
//
#include <hip/hip_runtime.h>
#include <hip/hip_bf16.h>

// Problem constants
#define HDIM   2880
#define NH     64
#define NKV    8
#define DHEAD  64
#define GQ     (NH / NKV)     // 8
#define WIN    128
#define NTOK   1024
#define QKV_N  ((NH + 2 * NKV) * DHEAD)   // 5120
#define QCOLS  (NH * DHEAD)               // 4096
#define KOFF   QCOLS                      // 4096
#define VOFF   (QCOLS + NKV * DHEAD)      // 4608

typedef __attribute__((ext_vector_type(8))) short short8;
typedef __attribute__((ext_vector_type(4))) float floatx4;

// Static device scratch (zero-init at module load).
__device__ unsigned short g_Xb   [(size_t)NTOK  * HDIM];          //  5.9 MB
__device__ unsigned short g_qkvb [(size_t)NTOK  * QKV_N];         // 10.5 MB bf16 qkv (post-rope)
__device__ unsigned short g_attn [(size_t)NTOK  * QCOLS];         //  8.4 MB
__device__ unsigned short g_WqkvT[(size_t)QKV_N * HDIM];          // 29.5 MB
__device__ unsigned short g_WoT  [(size_t)HDIM * QCOLS];          // 23.6 MB

__device__ __forceinline__ unsigned short f2b(float f) {
    __hip_bfloat16 h = __float2bfloat16(f);
    return *reinterpret_cast<unsigned short*>(&h);
}

__device__ __forceinline__ void gload_lds16(const unsigned short* g, unsigned short* l) {
    __builtin_amdgcn_global_load_lds(
        (const __attribute__((address_space(1))) unsigned int*)g,
        (__attribute__((address_space(3))) unsigned int*)l, 16, 0, 0);
}

// ---------------------------------------------------------------------------
// Transpose + cvt tile body: in (K x N f32) tile (bk,bn) -> out (N x K bf16).
// ---------------------------------------------------------------------------
__device__ __forceinline__ void transpose_tile(
        const float* __restrict__ in, unsigned short* __restrict__ out,
        int K, int N, int bk, int bn, int t, unsigned short* T) {
    #pragma unroll
    for (int i = 0; i < 4; ++i) {
        int c = i * 256 + t;          // float4 slots
        int r = c >> 4, cc = (c & 15) * 4;
        float4 v = *(const float4*)(in + (size_t)(bk * 64 + r) * N + bn * 64 + cc);
        T[r * 72 + cc + 0] = f2b(v.x);
        T[r * 72 + cc + 1] = f2b(v.y);
        T[r * 72 + cc + 2] = f2b(v.z);
        T[r * 72 + cc + 3] = f2b(v.w);
    }
    __syncthreads();
    #pragma unroll
    for (int i = 0; i < 2; ++i) {
        int c = i * 256 + t;
        int rn = c >> 3, kc = (c & 7) * 8;
        int4 vv;
        unsigned short* tp = (unsigned short*)&vv;
        #pragma unroll
        for (int j = 0; j < 8; ++j) tp[j] = T[(kc + j) * 72 + rn];
        *(int4*)(out + (size_t)(bn * 64 + rn) * K + bk * 64 + kc) = vv;
    }
}

// ---------------------------------------------------------------------------
// Merged prep: Wqkv transpose + Wo transpose + X f32->bf16 cvt.
// ---------------------------------------------------------------------------
#define NB_WQKV (45 * 80)     // 3600
#define NB_WO   (64 * 45)     // 2880
#define NB_CVT  (NTOK * HDIM / 4 / 256)   // 2880
__global__ __launch_bounds__(256) void prep(
        const float* __restrict__ X, const float* __restrict__ Wqkv,
        const float* __restrict__ Wo, unsigned short* __restrict__ Xb,
        unsigned short* __restrict__ WqkvT, unsigned short* __restrict__ WoT) {
    __shared__ __align__(16) unsigned short T[64 * 72];
    int id = blockIdx.x;
    int t = threadIdx.x;
    if (id < NB_WQKV) {
        transpose_tile(Wqkv, WqkvT, HDIM, QKV_N, id % 45, id / 45, t, T);
    } else if (id < NB_WQKV + NB_WO) {
        int id2 = id - NB_WQKV;
        transpose_tile(Wo, WoT, QCOLS, HDIM, id2 % 64, id2 / 64, t, T);
    } else {
        int gid = (id - NB_WQKV - NB_WO) * 256 + t;
        float4 v = *(const float4*)(X + (size_t)gid * 4);
        ushort4 o;
        o.x = f2b(v.x); o.y = f2b(v.y); o.z = f2b(v.z); o.w = f2b(v.w);
        *(ushort4*)(Xb + (size_t)gid * 4) = o;
    }
}

// ---------------------------------------------------------------------------
// Direct full-K GEMM, 128x64 tile, BK=64, 4 waves stacked in M (each wave
// 32 rows x 64 cols, acc 2x4 of 16x16 frags).
// A is NOT LDS-staged: each wave owns its 32 A-rows exclusively (zero
// cross-wave reuse), so A fragments are line-efficient global gathers
// (16 rows x 64 B contiguous per instr) hitting L2 — removes 16 KB staged
// + 32 KB read per block-step from the LDS pipe (72 -> 40 KB) and shrinks
// the per-step barrier drain from 6 to 2 outstanding loads.
// B stays LDS-staged (shared by all 4 waves), round-2 dbuf schedule,
// XOR-swizzled via inverse-permuted global source + permuted ds_read.
// XCD-aware bijective block swizzle (grid = 8*NBN, NBN col-tiles of 64).
// MODE 0: fused RoPE epilogue -> bf16 qkv (col tile == one head).
// MODE 1: plain f32 store to out (ld HDIM).
// ---------------------------------------------------------------------------
template<int KLEN, int MODE, int NBN>
__global__ __launch_bounds__(256) void gemm_dir(
        const unsigned short* __restrict__ A, const unsigned short* __restrict__ Bt,
        void* __restrict__ outp) {
    int d0 = blockIdx.x;                       // nwg = 8*NBN, nwg % 8 == 0
    int work = (d0 & 7) * NBN + (d0 >> 3);     // bijective XCD chunking
    int bm = work & 7, bn = work >> 3;         // 8 row tiles x NBN col tiles
    int t = threadIdx.x, lane = t & 63, wid = t >> 6;
    int quad = lane >> 4, ml = lane & 15;
    __shared__ __align__(16) unsigned short Bs[2][64 * 64];    // 2 x 8 KB
    floatx4 acc[2][4];
    #pragma unroll
    for (int i = 0; i < 2; ++i)
        #pragma unroll
        for (int j = 0; j < 4; ++j) acc[i][j] = (floatx4){0.f, 0.f, 0.f, 0.f};

    int srow = lane >> 3;                      // 0..7 within an 8-row group
    int scol = ((lane & 7) ^ srow) * 8;        // inverse-swizzled source unit
    // wave's exclusive A rows (gathered from global/L2, never staged)
    const unsigned short* Aw = A + (size_t)(bm * 128 + wid * 32) * KLEN;
    const unsigned short* Bb = Bt + (size_t)(bn * 64) * KLEN;

    constexpr int NT = KLEN / 64;

    // prologue: stage B tile 0 into buffer 0
    #pragma unroll
    for (int j = 0; j < 2; ++j) {
        int grp = wid * 2 + j;
        int r = grp * 8 + srow;
        gload_lds16(Bb + (size_t)r * KLEN + scol, &Bs[0][grp * 512]);
    }
    __syncthreads();

    for (int ti = 0; ti < NT; ++ti) {
        int cur = ti & 1;
        int k0 = ti * 64;
        if (ti + 1 < NT) {                     // issue next B-tile loads first
            int nxt = cur ^ 1;
            #pragma unroll
            for (int j = 0; j < 2; ++j) {
                int grp = wid * 2 + j;
                int r = grp * 8 + srow;
                gload_lds16(Bb + (size_t)r * KLEN + (k0 + 64) + scol, &Bs[nxt][grp * 512]);
            }
        }
        // A fragments: line-efficient global gather (16 rows x 64 B / instr)
        short8 af[2][2];
        #pragma unroll
        for (int kx = 0; kx < 2; ++kx)
            #pragma unroll
            for (int mt = 0; mt < 2; ++mt)
                af[kx][mt] = *(const short8*)(Aw + (size_t)(mt * 16 + ml) * KLEN
                                              + k0 + kx * 32 + quad * 8);
        #pragma unroll
        for (int kx = 0; kx < 2; ++kx) {
            int usw = ((kx * 4 + quad) ^ (ml & 7)) * 8;
            short8 bf[4];
            #pragma unroll
            for (int nt = 0; nt < 4; ++nt)
                bf[nt] = *(const short8*)&Bs[cur][(nt * 16 + ml) * 64 + usw];
            #pragma unroll
            for (int mt = 0; mt < 2; ++mt)
                #pragma unroll
                for (int nt = 0; nt < 4; ++nt)
                    acc[mt][nt] = __builtin_amdgcn_mfma_f32_16x16x32_bf16(af[kx][mt], bf[nt], acc[mt][nt], 0, 0, 0);
        }
        __syncthreads();   // drains this wave's vmcnt (2 staged loads) + read fence
    }

    if constexpr (MODE == 0) {
        // col tile bn == head bn; heads 0..71 are q/k (RoPE), 72..79 are v.
        unsigned short* qp = (unsigned short*)outp;
        int cb = bn * 64;
        if (bn < NH + NKV) {
            // inv_freq for this lane's two d values (d = ml, d = 16+ml)
            float inv0 = expf(-(float)ml * 0.3724497053f);          // theta^(-d/32)
            float inv1 = expf(-(float)(16 + ml) * 0.3724497053f);
            #pragma unroll
            for (int mt = 0; mt < 2; ++mt) {
                #pragma unroll
                for (int r = 0; r < 4; ++r) {
                    int n = bm * 128 + wid * 32 + mt * 16 + quad * 4 + r;
                    unsigned short* op = qp + (size_t)n * QKV_N + cb;
                    float s0, c0, s1, c1;
                    sincosf((float)n * inv0, &s0, &c0);
                    sincosf((float)n * inv1, &s1, &c1);
                    float x1a = acc[mt][0][r], x2a = acc[mt][2][r];
                    float x1b = acc[mt][1][r], x2b = acc[mt][3][r];
                    op[ml]           = f2b(x1a * c0 - x2a * s0);
                    op[ml + 32]      = f2b(x2a * c0 + x1a * s0);
                    op[16 + ml]      = f2b(x1b * c1 - x2b * s1);
                    op[16 + ml + 32] = f2b(x2b * c1 + x1b * s1);
                }
            }
        } else {
            #pragma unroll
            for (int mt = 0; mt < 2; ++mt)
                #pragma unroll
                for (int r = 0; r < 4; ++r) {
                    int n = bm * 128 + wid * 32 + mt * 16 + quad * 4 + r;
                    unsigned short* op = qp + (size_t)n * QKV_N + cb;
                    #pragma unroll
                    for (int nt = 0; nt < 4; ++nt)
                        op[nt * 16 + ml] = f2b(acc[mt][nt][r]);
                }
        }
    } else {
        float* op0 = (float*)outp;
        #pragma unroll
        for (int mt = 0; mt < 2; ++mt)
            #pragma unroll
            for (int r = 0; r < 4; ++r) {
                int n = bm * 128 + wid * 32 + mt * 16 + quad * 4 + r;
                float* op = op0 + (size_t)n * HDIM + bn * 64;
                #pragma unroll
                for (int nt = 0; nt < 4; ++nt)
                    op[nt * 16 + ml] = acc[mt][nt][r];
            }
    }
}

// ---------------------------------------------------------------------------
// MFMA flash-style sliding-window attention with sinks, bf16 in/out.
// [r5 version — best measured config] 1D grid 512 with XCD swizzle: each
// XCD owns one kv-head. Block = (16-token Q-tile, kv-head); M = 8 heads x
// 16 tokens = 128 rows; wave w owns rows [w*32, w*32+32).
// K is NOT LDS-staged (per-XCD K-slice is 128 KB, L2-resident); QK^T
// B-fragments are per-lane 16-B gathers from L2. Only V (transposed) + Ps
// use LDS -> 42 KB, 3 blocks/CU.
// ---------------------------------------------------------------------------
#define TQ     16
#define VT_LD  168
#define PS_LD  168

__global__ __launch_bounds__(256) void attn_mfma(
        const unsigned short* __restrict__ qkvb,
        const float* __restrict__ sinks,
        unsigned short* __restrict__ aout) {
    int d0 = blockIdx.x;                       // 512 blocks
    int work = (d0 & 7) * 64 + (d0 >> 3);      // bijective: XCD x -> kh == x
    int t0 = (work & 63) * TQ, kh = work >> 6;
    int t = threadIdx.x, lane = t & 63, wid = t >> 6;
    int quad = lane >> 4, ml = lane & 15;
    int wavebase = wid * 32;

    __shared__ __align__(16) unsigned short Vt[DHEAD * VT_LD];    // 21 KB
    __shared__ __align__(16) unsigned short Ps[4 * 16 * PS_LD];   // 21 KB
    unsigned short* Psw = &Ps[wid * 16 * PS_LD];

    // ---- stage V only (transposed), straight bf16 copies
    #pragma unroll
    for (int i = 0; i < 5; ++i) {
        int c = i * 256 + t;              // 0..1279 ushort8 slots
        int w = c >> 3, d8 = (c & 7) * 8;
        int r = t0 - 127 + w;
        r = min(max(r, 0), NTOK - 1);
        int4 vv = *(const int4*)(qkvb + (size_t)r * QKV_N + VOFF + kh * DHEAD + d8);
        const unsigned short* vp = (const unsigned short*)&vv;
        #pragma unroll
        for (int j = 0; j < 8; ++j) Vt[(d8 + j) * VT_LD + w] = vp[j];
    }
    __syncthreads();

    // ---- Q A-fragments straight from global bf16
    short8 qf[2][2];
    #pragma unroll
    for (int mt = 0; mt < 2; ++mt) {
        int m = wavebase + mt * 16 + ml;
        int tl = m & 15, g = m >> 4;
        const unsigned short* qp = qkvb + (size_t)(t0 + tl) * QKV_N + (kh * GQ + g) * DHEAD;
        #pragma unroll
        for (int kk = 0; kk < 2; ++kk)
            qf[mt][kk] = *(const short8*)(qp + kk * 32 + quad * 8);
    }

    // ---- S = Q K^T, K fragments gathered from global (L2-hit)
    const unsigned short* Kbase = qkvb + KOFF + kh * DHEAD;
    floatx4 S[2][10];
    #pragma unroll
    for (int mt = 0; mt < 2; ++mt)
        #pragma unroll
        for (int nt = 0; nt < 10; ++nt) S[mt][nt] = (floatx4){0.f, 0.f, 0.f, 0.f};
    #pragma unroll
    for (int kk = 0; kk < 2; ++kk) {
        #pragma unroll
        for (int nt = 0; nt < 10; ++nt) {
            int r = t0 - 127 + nt * 16 + ml;
            r = min(max(r, 0), NTOK - 1);
            short8 kb = *(const short8*)(Kbase + (size_t)r * QKV_N + kk * 32 + quad * 8);
            #pragma unroll
            for (int mt = 0; mt < 2; ++mt)
                S[mt][nt] = __builtin_amdgcn_mfma_f32_16x16x32_bf16(qf[mt][kk], kb, S[mt][nt], 0, 0, 0);
        }
    }

    // ---- band mask + scale   (valid: w>=tl, w<=tl+127, w>=127-t0)
    int wmin0 = 127 - t0;
    #pragma unroll
    for (int mt = 0; mt < 2; ++mt) {
        #pragma unroll
        for (int r = 0; r < 4; ++r) {
            int tl = (wavebase + mt * 16 + quad * 4 + r) & 15;
            int wlo = tl > wmin0 ? tl : wmin0;
            int whi = tl + 127;
            #pragma unroll
            for (int nt = 0; nt < 10; ++nt) {
                int w = nt * 16 + ml;
                float s = S[mt][nt][r] * 0.125f;
                S[mt][nt][r] = (w >= wlo && w <= whi) ? s : -INFINITY;
            }
        }
    }

    // ---- softmax with sink (rows spread over 16 lanes of the quad)
    #pragma unroll
    for (int mt = 0; mt < 2; ++mt) {
        int g = (wavebase + mt * 16) >> 4;
        float sk = sinks[kh * GQ + g];
        #pragma unroll
        for (int r = 0; r < 4; ++r) {
            float rm = -INFINITY;
            #pragma unroll
            for (int nt = 0; nt < 10; ++nt) rm = fmaxf(rm, S[mt][nt][r]);
            #pragma unroll
            for (int off = 1; off < 16; off <<= 1) rm = fmaxf(rm, __shfl_xor(rm, off));
            rm = fmaxf(rm, sk);
            float sum = 0.f;
            #pragma unroll
            for (int nt = 0; nt < 10; ++nt) {
                float p = __expf(S[mt][nt][r] - rm);   // exp(-inf)=0 masks
                S[mt][nt][r] = p;
                sum += p;
            }
            #pragma unroll
            for (int off = 1; off < 16; off <<= 1) sum += __shfl_xor(sum, off);
            float inv = 1.f / (sum + __expf(sk - rm));
            #pragma unroll
            for (int nt = 0; nt < 10; ++nt) S[mt][nt][r] *= inv;
        }
    }

    // ---- PV one m-tile at a time through per-wave Ps (wave DS ops in-order)
    #pragma unroll
    for (int mt = 0; mt < 2; ++mt) {
        #pragma unroll
        for (int r = 0; r < 4; ++r) {
            int lr = quad * 4 + r;
            #pragma unroll
            for (int nt = 0; nt < 10; ++nt)
                Psw[lr * PS_LD + nt * 16 + ml] = f2b(S[mt][nt][r]);
        }
        floatx4 O[4];
        #pragma unroll
        for (int j = 0; j < 4; ++j) O[j] = (floatx4){0.f, 0.f, 0.f, 0.f};
        #pragma unroll
        for (int ks = 0; ks < 5; ++ks) {
            short8 pf = *(const short8*)&Psw[ml * PS_LD + ks * 32 + quad * 8];
            #pragma unroll
            for (int nt = 0; nt < 4; ++nt) {
                short8 vf = *(const short8*)&Vt[(nt * 16 + ml) * VT_LD + ks * 32 + quad * 8];
                O[nt] = __builtin_amdgcn_mfma_f32_16x16x32_bf16(pf, vf, O[nt], 0, 0, 0);
            }
        }
        #pragma unroll
        for (int r = 0; r < 4; ++r) {
            int mm = wavebase + mt * 16 + quad * 4 + r;
            int tl = mm & 15, g = mm >> 4;
            unsigned short* op = aout + (size_t)(t0 + tl) * QCOLS + (kh * GQ + g) * DHEAD;
            #pragma unroll
            for (int nt = 0; nt < 4; ++nt)
                op[nt * 16 + ml] = f2b(O[nt][r]);
        }
    }
}

// ---------------------------------------------------------------------------
extern "C" void kernel_launch(void* const* d_in, const int* in_sizes, int n_in,
                              void* d_out, int out_size, void* d_ws, size_t ws_size,
                              hipStream_t stream) {
    const float* X     = (const float*)d_in[0];  // 1024x2880 f32
    const float* Wqkv  = (const float*)d_in[1];  // 2880x5120 f32
    const float* Wo    = (const float*)d_in[2];  // 4096x2880 f32
    const float* sinks = (const float*)d_in[3];  // 64 f32
    float* out = (float*)d_out;                  // 1024x2880 f32

    unsigned short *Xb, *qkvb, *attn, *WqkvT, *WoT;
    hipGetSymbolAddress((void**)&Xb,    HIP_SYMBOL(g_Xb));
    hipGetSymbolAddress((void**)&qkvb,  HIP_SYMBOL(g_qkvb));
    hipGetSymbolAddress((void**)&attn,  HIP_SYMBOL(g_attn));
    hipGetSymbolAddress((void**)&WqkvT, HIP_SYMBOL(g_WqkvT));
    hipGetSymbolAddress((void**)&WoT,   HIP_SYMBOL(g_WoT));

    // Merged cvt + both weight transposes (one launch)
    prep<<<NB_WQKV + NB_WO + NB_CVT, 256, 0, stream>>>(X, Wqkv, Wo, Xb, WqkvT, WoT);

    // QKV projection, fused RoPE -> bf16 qkv (640 blocks)
    gemm_dir<HDIM, 0, QKV_N / 64><<<8 * (QKV_N / 64), 256, 0, stream>>>(Xb, WqkvT, qkvb);

    // MFMA sliding-window attention -> bf16 attn (512 blocks)
    attn_mfma<<<512, 256, 0, stream>>>(qkvb, sinks, attn);

    // Output projection -> f32 out (360 blocks)
    gemm_dir<QCOLS, 1, HDIM / 64><<<8 * (HDIM / 64), 256, 0, stream>>>(attn, WoT, out);
}

// Round 10
// 310.855 us; speedup vs baseline: 1.1594x; 1.0537x over previous
//
#include <hip/hip_runtime.h>
#include <hip/hip_bf16.h>

// Problem constants
#define HDIM   2880
#define NH     64
#define NKV    8
#define DHEAD  64
#define GQ     (NH / NKV)     // 8
#define WIN    128
#define NTOK   1024
#define QKV_N  ((NH + 2 * NKV) * DHEAD)   // 5120
#define QCOLS  (NH * DHEAD)               // 4096
#define KOFF   QCOLS                      // 4096
#define VOFF   (QCOLS + NKV * DHEAD)      // 4608

typedef __attribute__((ext_vector_type(8))) short short8;
typedef __attribute__((ext_vector_type(4))) float floatx4;

// Static device scratch (zero-init at module load).
__device__ unsigned short g_Xb   [(size_t)NTOK  * HDIM];          //  5.9 MB
__device__ unsigned short g_qkvb [(size_t)NTOK  * QKV_N];         // 10.5 MB bf16 qkv (post-rope)
__device__ unsigned short g_attn [(size_t)NTOK  * QCOLS];         //  8.4 MB
__device__ unsigned short g_WqkvT[(size_t)QKV_N * HDIM];          // 29.5 MB
__device__ unsigned short g_WoT  [(size_t)HDIM * QCOLS];          // 23.6 MB

__device__ __forceinline__ unsigned short f2b(float f) {
    __hip_bfloat16 h = __float2bfloat16(f);
    return *reinterpret_cast<unsigned short*>(&h);
}

__device__ __forceinline__ void gload_lds16(const unsigned short* g, unsigned short* l) {
    __builtin_amdgcn_global_load_lds(
        (const __attribute__((address_space(1))) unsigned int*)g,
        (__attribute__((address_space(3))) unsigned int*)l, 16, 0, 0);
}

// ---------------------------------------------------------------------------
// Transpose + cvt tile body: in (K x N f32) tile (bk,bn) -> out (N x K bf16).
// LDS conflict fix: element (k,n) stored at column ((n>>2 ^ (k>>3)&7)<<2)|(n&3).
// Writes stay 4-contiguous (8B-merged); the read phase (8 lanes sharing rn,
// k stride 8 -> old stride 1152B = 0 mod 128, 8-way conflict) now spreads
// across 8 banks via the XOR key (k>>3)&7.
// ---------------------------------------------------------------------------
__device__ __forceinline__ void transpose_tile(
        const float* __restrict__ in, unsigned short* __restrict__ out,
        int K, int N, int bk, int bn, int t, unsigned short* T) {
    #pragma unroll
    for (int i = 0; i < 4; ++i) {
        int c = i * 256 + t;          // float4 slots
        int r = c >> 4, cc = (c & 15) * 4;
        float4 v = *(const float4*)(in + (size_t)(bk * 64 + r) * N + bn * 64 + cc);
        int col = (((cc >> 2) ^ ((r >> 3) & 7)) << 2);   // swizzled 4-unit
        T[r * 72 + col + 0] = f2b(v.x);
        T[r * 72 + col + 1] = f2b(v.y);
        T[r * 72 + col + 2] = f2b(v.z);
        T[r * 72 + col + 3] = f2b(v.w);
    }
    __syncthreads();
    #pragma unroll
    for (int i = 0; i < 2; ++i) {
        int c = i * 256 + t;
        int rn = c >> 3, kc = (c & 7) * 8;
        int s = (kc >> 3) & 7;                            // const per lane
        int col = ((((rn >> 2) ^ s) << 2) | (rn & 3));
        int4 vv;
        unsigned short* tp = (unsigned short*)&vv;
        #pragma unroll
        for (int j = 0; j < 8; ++j) tp[j] = T[(kc + j) * 72 + col];
        *(int4*)(out + (size_t)(bn * 64 + rn) * K + bk * 64 + kc) = vv;
    }
}

// ---------------------------------------------------------------------------
// Merged prep: Wqkv transpose + Wo transpose + X f32->bf16 cvt.
// ---------------------------------------------------------------------------
#define NB_WQKV (45 * 80)     // 3600
#define NB_WO   (64 * 45)     // 2880
#define NB_CVT  (NTOK * HDIM / 4 / 256)   // 2880
__global__ __launch_bounds__(256) void prep(
        const float* __restrict__ X, const float* __restrict__ Wqkv,
        const float* __restrict__ Wo, unsigned short* __restrict__ Xb,
        unsigned short* __restrict__ WqkvT, unsigned short* __restrict__ WoT) {
    __shared__ __align__(16) unsigned short T[64 * 72];
    int id = blockIdx.x;
    int t = threadIdx.x;
    if (id < NB_WQKV) {
        transpose_tile(Wqkv, WqkvT, HDIM, QKV_N, id % 45, id / 45, t, T);
    } else if (id < NB_WQKV + NB_WO) {
        int id2 = id - NB_WQKV;
        transpose_tile(Wo, WoT, QCOLS, HDIM, id2 % 64, id2 / 64, t, T);
    } else {
        int gid = (id - NB_WQKV - NB_WO) * 256 + t;
        float4 v = *(const float4*)(X + (size_t)gid * 4);
        ushort4 o;
        o.x = f2b(v.x); o.y = f2b(v.y); o.z = f2b(v.z); o.w = f2b(v.w);
        *(ushort4*)(Xb + (size_t)gid * 4) = o;
    }
}

// ---------------------------------------------------------------------------
// Direct full-K GEMM, 128x64 tile, BK=64, 4 waves stacked in M (each wave
// 32 rows x 64 cols, acc 2x4 of 16x16 frags).  [round-2 schedule: proven
// local optimum — counted-vmcnt x2, 128x128 tile, and A-from-global all
// regressed against it]
// 2-phase double-buffered: STAGE(next) issued before compute(cur); one
// __syncthreads per K-step. LDS XOR-swizzle via inverse-permuted global
// source (global_load_lds dest stays linear) + permuted ds_read address.
// XCD-aware bijective block swizzle (grid = 8*NBN, NBN col-tiles of 64).
// MODE 0: fused RoPE epilogue -> bf16 qkv (col tile == one head).
// MODE 1: plain f32 store to out (ld HDIM).
// ---------------------------------------------------------------------------
template<int KLEN, int MODE, int NBN>
__global__ __launch_bounds__(256) void gemm_dir(
        const unsigned short* __restrict__ A, const unsigned short* __restrict__ Bt,
        void* __restrict__ outp) {
    int d0 = blockIdx.x;                       // nwg = 8*NBN, nwg % 8 == 0
    int work = (d0 & 7) * NBN + (d0 >> 3);     // bijective XCD chunking
    int bm = work & 7, bn = work >> 3;         // 8 row tiles x NBN col tiles
    int t = threadIdx.x, lane = t & 63, wid = t >> 6;
    int quad = lane >> 4, ml = lane & 15;
    __shared__ __align__(16) unsigned short As[2][128 * 64];   // 2 x 16 KB
    __shared__ __align__(16) unsigned short Bs[2][64 * 64];    // 2 x  8 KB
    floatx4 acc[2][4];
    #pragma unroll
    for (int i = 0; i < 2; ++i)
        #pragma unroll
        for (int j = 0; j < 4; ++j) acc[i][j] = (floatx4){0.f, 0.f, 0.f, 0.f};

    int srow = lane >> 3;                      // 0..7 within an 8-row group
    int scol = ((lane & 7) ^ srow) * 8;        // inverse-swizzled source unit
    const unsigned short* Ab = A  + (size_t)(bm * 128) * KLEN;
    const unsigned short* Bb = Bt + (size_t)(bn * 64) * KLEN;

    constexpr int NT = KLEN / 64;

    // prologue: stage tile 0 into buffer 0
    #pragma unroll
    for (int j = 0; j < 4; ++j) {
        int grp = wid * 4 + j;
        int r = grp * 8 + srow;
        gload_lds16(Ab + (size_t)r * KLEN + scol, &As[0][grp * 512]);
    }
    #pragma unroll
    for (int j = 0; j < 2; ++j) {
        int grp = wid * 2 + j;
        int r = grp * 8 + srow;
        gload_lds16(Bb + (size_t)r * KLEN + scol, &Bs[0][grp * 512]);
    }
    __syncthreads();

    for (int ti = 0; ti < NT; ++ti) {
        int cur = ti & 1;
        if (ti + 1 < NT) {                     // issue next-tile loads first
            int k0 = (ti + 1) * 64;
            int nxt = cur ^ 1;
            #pragma unroll
            for (int j = 0; j < 4; ++j) {
                int grp = wid * 4 + j;
                int r = grp * 8 + srow;
                gload_lds16(Ab + (size_t)r * KLEN + k0 + scol, &As[nxt][grp * 512]);
            }
            #pragma unroll
            for (int j = 0; j < 2; ++j) {
                int grp = wid * 2 + j;
                int r = grp * 8 + srow;
                gload_lds16(Bb + (size_t)r * KLEN + k0 + scol, &Bs[nxt][grp * 512]);
            }
        }
        #pragma unroll
        for (int kk = 0; kk < 64; kk += 32) {
            const int ub = kk >> 3;            // 0 or 4
            int usw = ((ub + quad) ^ (ml & 7)) * 8;
            short8 af[2], bf[4];
            #pragma unroll
            for (int mt = 0; mt < 2; ++mt)
                af[mt] = *(const short8*)&As[cur][(wid * 32 + mt * 16 + ml) * 64 + usw];
            #pragma unroll
            for (int nt = 0; nt < 4; ++nt)
                bf[nt] = *(const short8*)&Bs[cur][(nt * 16 + ml) * 64 + usw];
            #pragma unroll
            for (int mt = 0; mt < 2; ++mt)
                #pragma unroll
                for (int nt = 0; nt < 4; ++nt)
                    acc[mt][nt] = __builtin_amdgcn_mfma_f32_16x16x32_bf16(af[mt], bf[nt], acc[mt][nt], 0, 0, 0);
        }
        __syncthreads();   // drains this wave's vmcnt (next tile staged) + read fence
    }

    if constexpr (MODE == 0) {
        // col tile bn == head bn; heads 0..71 are q/k (RoPE), 72..79 are v.
        unsigned short* qp = (unsigned short*)outp;
        int cb = bn * 64;
        if (bn < NH + NKV) {
            // inv_freq for this lane's two d values (d = ml, d = 16+ml)
            float inv0 = expf(-(float)ml * 0.3724497053f);          // theta^(-d/32)
            float inv1 = expf(-(float)(16 + ml) * 0.3724497053f);
            #pragma unroll
            for (int mt = 0; mt < 2; ++mt) {
                #pragma unroll
                for (int r = 0; r < 4; ++r) {
                    int n = bm * 128 + wid * 32 + mt * 16 + quad * 4 + r;
                    unsigned short* op = qp + (size_t)n * QKV_N + cb;
                    float s0, c0, s1, c1;
                    sincosf((float)n * inv0, &s0, &c0);
                    sincosf((float)n * inv1, &s1, &c1);
                    float x1a = acc[mt][0][r], x2a = acc[mt][2][r];
                    float x1b = acc[mt][1][r], x2b = acc[mt][3][r];
                    op[ml]           = f2b(x1a * c0 - x2a * s0);
                    op[ml + 32]      = f2b(x2a * c0 + x1a * s0);
                    op[16 + ml]      = f2b(x1b * c1 - x2b * s1);
                    op[16 + ml + 32] = f2b(x2b * c1 + x1b * s1);
                }
            }
        } else {
            #pragma unroll
            for (int mt = 0; mt < 2; ++mt)
                #pragma unroll
                for (int r = 0; r < 4; ++r) {
                    int n = bm * 128 + wid * 32 + mt * 16 + quad * 4 + r;
                    unsigned short* op = qp + (size_t)n * QKV_N + cb;
                    #pragma unroll
                    for (int nt = 0; nt < 4; ++nt)
                        op[nt * 16 + ml] = f2b(acc[mt][nt][r]);
                }
        }
    } else {
        float* op0 = (float*)outp;
        #pragma unroll
        for (int mt = 0; mt < 2; ++mt)
            #pragma unroll
            for (int r = 0; r < 4; ++r) {
                int n = bm * 128 + wid * 32 + mt * 16 + quad * 4 + r;
                float* op = op0 + (size_t)n * HDIM + bn * 64;
                #pragma unroll
                for (int nt = 0; nt < 4; ++nt)
                    op[nt * 16 + ml] = acc[mt][nt][r];
            }
    }
}

// ---------------------------------------------------------------------------
// MFMA flash-style sliding-window attention with sinks, bf16 in/out.
// [r5 structure] 1D grid 512 with XCD swizzle: each XCD owns one kv-head.
// Block = (16-token Q-tile, kv-head); wave w owns rows [w*32, w*32+32).
// K is NOT LDS-staged (per-XCD K-slice is L2-resident); QK^T B-fragments
// are per-lane 16-B gathers from L2. V (transposed) + Ps in LDS.
// V-staging conflict fix: element (d,w) stored at w-unit (w>>3)^((d>>3)&7)
// (old layout: 8 lanes with d stride 8 -> row stride 2688B = 0 mod 128,
// 8-way conflict on all 40 scalar writes/lane). VT_LD=200 keeps the PV
// b128 reads bank-staggered (row 400B = 4 dwords mod 32).
// ---------------------------------------------------------------------------
#define TQ     16
#define VT_LD  200
#define PS_LD  168

__global__ __launch_bounds__(256) void attn_mfma(
        const unsigned short* __restrict__ qkvb,
        const float* __restrict__ sinks,
        unsigned short* __restrict__ aout) {
    int d0 = blockIdx.x;                       // 512 blocks
    int work = (d0 & 7) * 64 + (d0 >> 3);      // bijective: XCD x -> kh == x
    int t0 = (work & 63) * TQ, kh = work >> 6;
    int t = threadIdx.x, lane = t & 63, wid = t >> 6;
    int quad = lane >> 4, ml = lane & 15;
    int wavebase = wid * 32;

    __shared__ __align__(16) unsigned short Vt[DHEAD * VT_LD];    // 25.6 KB
    __shared__ __align__(16) unsigned short Ps[4 * 16 * PS_LD];   // 21   KB
    unsigned short* Psw = &Ps[wid * 16 * PS_LD];

    // ---- stage V only (transposed), swizzled w-unit (conflict-free writes)
    #pragma unroll
    for (int i = 0; i < 5; ++i) {
        int c = i * 256 + t;              // 0..1279 ushort8 slots
        int w = c >> 3, d8 = (c & 7) * 8;
        int r = t0 - 127 + w;
        r = min(max(r, 0), NTOK - 1);
        int4 vv = *(const int4*)(qkvb + (size_t)r * QKV_N + VOFF + kh * DHEAD + d8);
        const unsigned short* vp = (const unsigned short*)&vv;
        int wc = ((((w >> 3) ^ (d8 >> 3)) << 3) | (w & 7));   // swizzled col
        #pragma unroll
        for (int j = 0; j < 8; ++j) Vt[(d8 + j) * VT_LD + wc] = vp[j];
    }
    __syncthreads();

    // ---- Q A-fragments straight from global bf16
    short8 qf[2][2];
    #pragma unroll
    for (int mt = 0; mt < 2; ++mt) {
        int m = wavebase + mt * 16 + ml;
        int tl = m & 15, g = m >> 4;
        const unsigned short* qp = qkvb + (size_t)(t0 + tl) * QKV_N + (kh * GQ + g) * DHEAD;
        #pragma unroll
        for (int kk = 0; kk < 2; ++kk)
            qf[mt][kk] = *(const short8*)(qp + kk * 32 + quad * 8);
    }

    // ---- S = Q K^T, K fragments gathered from global (L2-hit)
    const unsigned short* Kbase = qkvb + KOFF + kh * DHEAD;
    floatx4 S[2][10];
    #pragma unroll
    for (int mt = 0; mt < 2; ++mt)
        #pragma unroll
        for (int nt = 0; nt < 10; ++nt) S[mt][nt] = (floatx4){0.f, 0.f, 0.f, 0.f};
    #pragma unroll
    for (int kk = 0; kk < 2; ++kk) {
        #pragma unroll
        for (int nt = 0; nt < 10; ++nt) {
            int r = t0 - 127 + nt * 16 + ml;
            r = min(max(r, 0), NTOK - 1);
            short8 kb = *(const short8*)(Kbase + (size_t)r * QKV_N + kk * 32 + quad * 8);
            #pragma unroll
            for (int mt = 0; mt < 2; ++mt)
                S[mt][nt] = __builtin_amdgcn_mfma_f32_16x16x32_bf16(qf[mt][kk], kb, S[mt][nt], 0, 0, 0);
        }
    }

    // ---- band mask + scale   (valid: w>=tl, w<=tl+127, w>=127-t0)
    int wmin0 = 127 - t0;
    #pragma unroll
    for (int mt = 0; mt < 2; ++mt) {
        #pragma unroll
        for (int r = 0; r < 4; ++r) {
            int tl = (wavebase + mt * 16 + quad * 4 + r) & 15;
            int wlo = tl > wmin0 ? tl : wmin0;
            int whi = tl + 127;
            #pragma unroll
            for (int nt = 0; nt < 10; ++nt) {
                int w = nt * 16 + ml;
                float s = S[mt][nt][r] * 0.125f;
                S[mt][nt][r] = (w >= wlo && w <= whi) ? s : -INFINITY;
            }
        }
    }

    // ---- softmax with sink (rows spread over 16 lanes of the quad)
    #pragma unroll
    for (int mt = 0; mt < 2; ++mt) {
        int g = (wavebase + mt * 16) >> 4;
        float sk = sinks[kh * GQ + g];
        #pragma unroll
        for (int r = 0; r < 4; ++r) {
            float rm = -INFINITY;
            #pragma unroll
            for (int nt = 0; nt < 10; ++nt) rm = fmaxf(rm, S[mt][nt][r]);
            #pragma unroll
            for (int off = 1; off < 16; off <<= 1) rm = fmaxf(rm, __shfl_xor(rm, off));
            rm = fmaxf(rm, sk);
            float sum = 0.f;
            #pragma unroll
            for (int nt = 0; nt < 10; ++nt) {
                float p = __expf(S[mt][nt][r] - rm);   // exp(-inf)=0 masks
                S[mt][nt][r] = p;
                sum += p;
            }
            #pragma unroll
            for (int off = 1; off < 16; off <<= 1) sum += __shfl_xor(sum, off);
            float inv = 1.f / (sum + __expf(sk - rm));
            #pragma unroll
            for (int nt = 0; nt < 10; ++nt) S[mt][nt][r] *= inv;
        }
    }

    // ---- PV one m-tile at a time through per-wave Ps (wave DS ops in-order)
    #pragma unroll
    for (int mt = 0; mt < 2; ++mt) {
        #pragma unroll
        for (int r = 0; r < 4; ++r) {
            int lr = quad * 4 + r;
            #pragma unroll
            for (int nt = 0; nt < 10; ++nt)
                Psw[lr * PS_LD + nt * 16 + ml] = f2b(S[mt][nt][r]);
        }
        floatx4 O[4];
        #pragma unroll
        for (int j = 0; j < 4; ++j) O[j] = (floatx4){0.f, 0.f, 0.f, 0.f};
        #pragma unroll
        for (int ks = 0; ks < 5; ++ks) {
            short8 pf = *(const short8*)&Psw[ml * PS_LD + ks * 32 + quad * 8];
            #pragma unroll
            for (int nt = 0; nt < 4; ++nt) {
                int d = nt * 16 + ml;
                int u = ((ks * 4 + quad) ^ ((d >> 3) & 7)) << 3;   // swizzled unit
                short8 vf = *(const short8*)&Vt[d * VT_LD + u];
                O[nt] = __builtin_amdgcn_mfma_f32_16x16x32_bf16(pf, vf, O[nt], 0, 0, 0);
            }
        }
        #pragma unroll
        for (int r = 0; r < 4; ++r) {
            int mm = wavebase + mt * 16 + quad * 4 + r;
            int tl = mm & 15, g = mm >> 4;
            unsigned short* op = aout + (size_t)(t0 + tl) * QCOLS + (kh * GQ + g) * DHEAD;
            #pragma unroll
            for (int nt = 0; nt < 4; ++nt)
                op[nt * 16 + ml] = f2b(O[nt][r]);
        }
    }
}

// ---------------------------------------------------------------------------
extern "C" void kernel_launch(void* const* d_in, const int* in_sizes, int n_in,
                              void* d_out, int out_size, void* d_ws, size_t ws_size,
                              hipStream_t stream) {
    const float* X     = (const float*)d_in[0];  // 1024x2880 f32
    const float* Wqkv  = (const float*)d_in[1];  // 2880x5120 f32
    const float* Wo    = (const float*)d_in[2];  // 4096x2880 f32
    const float* sinks = (const float*)d_in[3];  // 64 f32
    float* out = (float*)d_out;                  // 1024x2880 f32

    unsigned short *Xb, *qkvb, *attn, *WqkvT, *WoT;
    hipGetSymbolAddress((void**)&Xb,    HIP_SYMBOL(g_Xb));
    hipGetSymbolAddress((void**)&qkvb,  HIP_SYMBOL(g_qkvb));
    hipGetSymbolAddress((void**)&attn,  HIP_SYMBOL(g_attn));
    hipGetSymbolAddress((void**)&WqkvT, HIP_SYMBOL(g_WqkvT));
    hipGetSymbolAddress((void**)&WoT,   HIP_SYMBOL(g_WoT));

    // Merged cvt + both weight transposes (one launch)
    prep<<<NB_WQKV + NB_WO + NB_CVT, 256, 0, stream>>>(X, Wqkv, Wo, Xb, WqkvT, WoT);

    // QKV projection, fused RoPE -> bf16 qkv (640 blocks)
    gemm_dir<HDIM, 0, QKV_N / 64><<<8 * (QKV_N / 64), 256, 0, stream>>>(Xb, WqkvT, qkvb);

    // MFMA sliding-window attention -> bf16 attn (512 blocks)
    attn_mfma<<<512, 256, 0, stream>>>(qkvb, sinks, attn);

    // Output projection -> f32 out (360 blocks)
    gemm_dir<QCOLS, 1, HDIM / 64><<<8 * (HDIM / 64), 256, 0, stream>>>(attn, WoT, out);
}

// Round 11
// 307.805 us; speedup vs baseline: 1.1709x; 1.0099x over previous
//
#include <hip/hip_runtime.h>
#include <hip/hip_bf16.h>

// Problem constants
#define HDIM   2880
#define NH     64
#define NKV    8
#define DHEAD  64
#define GQ     (NH / NKV)     // 8
#define WIN    128
#define NTOK   1024
#define QKV_N  ((NH + 2 * NKV) * DHEAD)   // 5120
#define QCOLS  (NH * DHEAD)               // 4096
#define KOFF   QCOLS                      // 4096
#define VOFF   (QCOLS + NKV * DHEAD)      // 4608

typedef __attribute__((ext_vector_type(8))) short short8;
typedef __attribute__((ext_vector_type(4))) float floatx4;

// Static device scratch (zero-init at module load).
__device__ unsigned short g_Xb   [(size_t)NTOK  * HDIM];          //  5.9 MB
__device__ unsigned short g_qkvb [(size_t)NTOK  * QKV_N];         // 10.5 MB bf16 qkv (post-rope)
__device__ unsigned short g_attn [(size_t)NTOK  * QCOLS];         //  8.4 MB
__device__ unsigned short g_WqkvT[(size_t)QKV_N * HDIM];          // 29.5 MB
__device__ unsigned short g_WoT  [(size_t)HDIM * QCOLS];          // 23.6 MB

__device__ __forceinline__ unsigned short f2b(float f) {
    __hip_bfloat16 h = __float2bfloat16(f);
    return *reinterpret_cast<unsigned short*>(&h);
}

__device__ __forceinline__ void gload_lds16(const unsigned short* g, unsigned short* l) {
    __builtin_amdgcn_global_load_lds(
        (const __attribute__((address_space(1))) unsigned int*)g,
        (__attribute__((address_space(3))) unsigned int*)l, 16, 0, 0);
}

// ---------------------------------------------------------------------------
// Transpose + cvt tile body: in (K x N f32) tile (bk,bn) -> out (N x K bf16).
// Conflict-free: element (k,n) at column ((n>>2 ^ (k>>3)&7)<<2)|(n&3)
// (8-row read stride 1152B = 0 mod 128 would be 8-way; XOR spreads it).
// ---------------------------------------------------------------------------
__device__ __forceinline__ void transpose_tile(
        const float* __restrict__ in, unsigned short* __restrict__ out,
        int K, int N, int bk, int bn, int t, unsigned short* T) {
    #pragma unroll
    for (int i = 0; i < 4; ++i) {
        int c = i * 256 + t;          // float4 slots
        int r = c >> 4, cc = (c & 15) * 4;
        float4 v = *(const float4*)(in + (size_t)(bk * 64 + r) * N + bn * 64 + cc);
        int col = (((cc >> 2) ^ ((r >> 3) & 7)) << 2);   // swizzled 4-unit
        T[r * 72 + col + 0] = f2b(v.x);
        T[r * 72 + col + 1] = f2b(v.y);
        T[r * 72 + col + 2] = f2b(v.z);
        T[r * 72 + col + 3] = f2b(v.w);
    }
    __syncthreads();
    #pragma unroll
    for (int i = 0; i < 2; ++i) {
        int c = i * 256 + t;
        int rn = c >> 3, kc = (c & 7) * 8;
        int s = (kc >> 3) & 7;                            // const per lane
        int col = ((((rn >> 2) ^ s) << 2) | (rn & 3));
        int4 vv;
        unsigned short* tp = (unsigned short*)&vv;
        #pragma unroll
        for (int j = 0; j < 8; ++j) tp[j] = T[(kc + j) * 72 + col];
        *(int4*)(out + (size_t)(bn * 64 + rn) * K + bk * 64 + kc) = vv;
    }
}

// ---------------------------------------------------------------------------
// prep1: Wqkv transpose (3600 blocks) + X f32->bf16 cvt (2880 blocks).
// The Wo transpose moved into attn_fused (it's only needed 2 kernels later).
// ---------------------------------------------------------------------------
#define NB_WQKV (45 * 80)     // 3600
#define NB_WO   (64 * 45)     // 2880
#define NB_CVT  (NTOK * HDIM / 4 / 256)   // 2880
__global__ __launch_bounds__(256) void prep1(
        const float* __restrict__ X, const float* __restrict__ Wqkv,
        unsigned short* __restrict__ Xb, unsigned short* __restrict__ WqkvT) {
    __shared__ __align__(16) unsigned short T[64 * 72];
    int id = blockIdx.x;
    int t = threadIdx.x;
    if (id < NB_WQKV) {
        transpose_tile(Wqkv, WqkvT, HDIM, QKV_N, id % 45, id / 45, t, T);
    } else {
        int gid = (id - NB_WQKV) * 256 + t;
        float4 v = *(const float4*)(X + (size_t)gid * 4);
        ushort4 o;
        o.x = f2b(v.x); o.y = f2b(v.y); o.z = f2b(v.z); o.w = f2b(v.w);
        *(ushort4*)(Xb + (size_t)gid * 4) = o;
    }
}

// ---------------------------------------------------------------------------
// Direct full-K GEMM, 128x64 tile, BK=64, 4 waves stacked in M (each wave
// 32 rows x 64 cols, acc 2x4 of 16x16 frags).  [round-2 schedule: proven
// local optimum — counted-vmcnt x2, 128x128 tile, and A-from-global all
// regressed against it]
// 2-phase double-buffered: STAGE(next) issued before compute(cur); one
// __syncthreads per K-step. LDS XOR-swizzle via inverse-permuted global
// source (global_load_lds dest stays linear) + permuted ds_read address.
// XCD-aware bijective block swizzle (grid = 8*NBN, NBN col-tiles of 64).
// MODE 0: fused RoPE epilogue -> bf16 qkv (col tile == one head).
// MODE 1: plain f32 store to out (ld HDIM).
// ---------------------------------------------------------------------------
template<int KLEN, int MODE, int NBN>
__global__ __launch_bounds__(256) void gemm_dir(
        const unsigned short* __restrict__ A, const unsigned short* __restrict__ Bt,
        void* __restrict__ outp) {
    int d0 = blockIdx.x;                       // nwg = 8*NBN, nwg % 8 == 0
    int work = (d0 & 7) * NBN + (d0 >> 3);     // bijective XCD chunking
    int bm = work & 7, bn = work >> 3;         // 8 row tiles x NBN col tiles
    int t = threadIdx.x, lane = t & 63, wid = t >> 6;
    int quad = lane >> 4, ml = lane & 15;
    __shared__ __align__(16) unsigned short As[2][128 * 64];   // 2 x 16 KB
    __shared__ __align__(16) unsigned short Bs[2][64 * 64];    // 2 x  8 KB
    floatx4 acc[2][4];
    #pragma unroll
    for (int i = 0; i < 2; ++i)
        #pragma unroll
        for (int j = 0; j < 4; ++j) acc[i][j] = (floatx4){0.f, 0.f, 0.f, 0.f};

    int srow = lane >> 3;                      // 0..7 within an 8-row group
    int scol = ((lane & 7) ^ srow) * 8;        // inverse-swizzled source unit
    const unsigned short* Ab = A  + (size_t)(bm * 128) * KLEN;
    const unsigned short* Bb = Bt + (size_t)(bn * 64) * KLEN;

    constexpr int NT = KLEN / 64;

    // prologue: stage tile 0 into buffer 0
    #pragma unroll
    for (int j = 0; j < 4; ++j) {
        int grp = wid * 4 + j;
        int r = grp * 8 + srow;
        gload_lds16(Ab + (size_t)r * KLEN + scol, &As[0][grp * 512]);
    }
    #pragma unroll
    for (int j = 0; j < 2; ++j) {
        int grp = wid * 2 + j;
        int r = grp * 8 + srow;
        gload_lds16(Bb + (size_t)r * KLEN + scol, &Bs[0][grp * 512]);
    }
    __syncthreads();

    for (int ti = 0; ti < NT; ++ti) {
        int cur = ti & 1;
        if (ti + 1 < NT) {                     // issue next-tile loads first
            int k0 = (ti + 1) * 64;
            int nxt = cur ^ 1;
            #pragma unroll
            for (int j = 0; j < 4; ++j) {
                int grp = wid * 4 + j;
                int r = grp * 8 + srow;
                gload_lds16(Ab + (size_t)r * KLEN + k0 + scol, &As[nxt][grp * 512]);
            }
            #pragma unroll
            for (int j = 0; j < 2; ++j) {
                int grp = wid * 2 + j;
                int r = grp * 8 + srow;
                gload_lds16(Bb + (size_t)r * KLEN + k0 + scol, &Bs[nxt][grp * 512]);
            }
        }
        #pragma unroll
        for (int kk = 0; kk < 64; kk += 32) {
            const int ub = kk >> 3;            // 0 or 4
            int usw = ((ub + quad) ^ (ml & 7)) * 8;
            short8 af[2], bf[4];
            #pragma unroll
            for (int mt = 0; mt < 2; ++mt)
                af[mt] = *(const short8*)&As[cur][(wid * 32 + mt * 16 + ml) * 64 + usw];
            #pragma unroll
            for (int nt = 0; nt < 4; ++nt)
                bf[nt] = *(const short8*)&Bs[cur][(nt * 16 + ml) * 64 + usw];
            #pragma unroll
            for (int mt = 0; mt < 2; ++mt)
                #pragma unroll
                for (int nt = 0; nt < 4; ++nt)
                    acc[mt][nt] = __builtin_amdgcn_mfma_f32_16x16x32_bf16(af[mt], bf[nt], acc[mt][nt], 0, 0, 0);
        }
        __syncthreads();   // drains this wave's vmcnt (next tile staged) + read fence
    }

    if constexpr (MODE == 0) {
        // col tile bn == head bn; heads 0..71 are q/k (RoPE), 72..79 are v.
        unsigned short* qp = (unsigned short*)outp;
        int cb = bn * 64;
        if (bn < NH + NKV) {
            // inv_freq for this lane's two d values (d = ml, d = 16+ml)
            float inv0 = expf(-(float)ml * 0.3724497053f);          // theta^(-d/32)
            float inv1 = expf(-(float)(16 + ml) * 0.3724497053f);
            #pragma unroll
            for (int mt = 0; mt < 2; ++mt) {
                #pragma unroll
                for (int r = 0; r < 4; ++r) {
                    int n = bm * 128 + wid * 32 + mt * 16 + quad * 4 + r;
                    unsigned short* op = qp + (size_t)n * QKV_N + cb;
                    float s0, c0, s1, c1;
                    sincosf((float)n * inv0, &s0, &c0);
                    sincosf((float)n * inv1, &s1, &c1);
                    float x1a = acc[mt][0][r], x2a = acc[mt][2][r];
                    float x1b = acc[mt][1][r], x2b = acc[mt][3][r];
                    op[ml]           = f2b(x1a * c0 - x2a * s0);
                    op[ml + 32]      = f2b(x2a * c0 + x1a * s0);
                    op[16 + ml]      = f2b(x1b * c1 - x2b * s1);
                    op[16 + ml + 32] = f2b(x2b * c1 + x1b * s1);
                }
            }
        } else {
            #pragma unroll
            for (int mt = 0; mt < 2; ++mt)
                #pragma unroll
                for (int r = 0; r < 4; ++r) {
                    int n = bm * 128 + wid * 32 + mt * 16 + quad * 4 + r;
                    unsigned short* op = qp + (size_t)n * QKV_N + cb;
                    #pragma unroll
                    for (int nt = 0; nt < 4; ++nt)
                        op[nt * 16 + ml] = f2b(acc[mt][nt][r]);
                }
        }
    } else {
        float* op0 = (float*)outp;
        #pragma unroll
        for (int mt = 0; mt < 2; ++mt)
            #pragma unroll
            for (int r = 0; r < 4; ++r) {
                int n = bm * 128 + wid * 32 + mt * 16 + quad * 4 + r;
                float* op = op0 + (size_t)n * HDIM + bn * 64;
                #pragma unroll
                for (int nt = 0; nt < 4; ++nt)
                    op[nt * 16 + ml] = acc[mt][nt][r];
            }
    }
}

// ---------------------------------------------------------------------------
// Fused kernel: attn (blocks 0..511) + Wo transpose (blocks 512..3391).
// The Wo transpose is only needed by the LAST gemm, so it runs concurrently
// in attn's latency bubbles (attn: 2-3 blocks/CU, latency-bound, idle pipes).
// LDS is one aliased buffer (attn: Vt+Ps = 46.6 KB; transpose: 9.2 KB).
// attn: [r5/r10 structure] XCD swizzle (kh == XCD), K from L2 gathers,
// V transposed+swizzled in LDS, Ps per-wave; s_setprio around MFMA clusters.
// ---------------------------------------------------------------------------
#define TQ     16
#define VT_LD  200
#define PS_LD  168
#define ATTN_NB 512

__global__ __launch_bounds__(256) void attn_fused(
        const unsigned short* __restrict__ qkvb,
        const float* __restrict__ sinks,
        unsigned short* __restrict__ aout,
        const float* __restrict__ Wo,
        unsigned short* __restrict__ WoT) {
    __shared__ __align__(16) unsigned short LDSb[DHEAD * VT_LD + 4 * 16 * PS_LD];
    int d0 = blockIdx.x;
    int t = threadIdx.x;

    if (d0 >= ATTN_NB) {                       // ---- Wo transpose branch
        int id2 = d0 - ATTN_NB;                // 0..2879
        transpose_tile(Wo, WoT, QCOLS, HDIM, id2 % 64, id2 / 64, t, LDSb);
        return;
    }

    // ---- attention branch
    int work = (d0 & 7) * 64 + (d0 >> 3);      // bijective: XCD x -> kh == x
    int t0 = (work & 63) * TQ, kh = work >> 6;
    int lane = t & 63, wid = t >> 6;
    int quad = lane >> 4, ml = lane & 15;
    int wavebase = wid * 32;

    unsigned short* Vt = LDSb;                               // 25.6 KB
    unsigned short* Ps = LDSb + DHEAD * VT_LD;               // 21   KB
    unsigned short* Psw = &Ps[wid * 16 * PS_LD];

    // ---- stage V only (transposed), swizzled w-unit (conflict-free writes)
    #pragma unroll
    for (int i = 0; i < 5; ++i) {
        int c = i * 256 + t;              // 0..1279 ushort8 slots
        int w = c >> 3, d8 = (c & 7) * 8;
        int r = t0 - 127 + w;
        r = min(max(r, 0), NTOK - 1);
        int4 vv = *(const int4*)(qkvb + (size_t)r * QKV_N + VOFF + kh * DHEAD + d8);
        const unsigned short* vp = (const unsigned short*)&vv;
        int wc = ((((w >> 3) ^ (d8 >> 3)) << 3) | (w & 7));   // swizzled col
        #pragma unroll
        for (int j = 0; j < 8; ++j) Vt[(d8 + j) * VT_LD + wc] = vp[j];
    }
    __syncthreads();

    // ---- Q A-fragments straight from global bf16
    short8 qf[2][2];
    #pragma unroll
    for (int mt = 0; mt < 2; ++mt) {
        int m = wavebase + mt * 16 + ml;
        int tl = m & 15, g = m >> 4;
        const unsigned short* qp = qkvb + (size_t)(t0 + tl) * QKV_N + (kh * GQ + g) * DHEAD;
        #pragma unroll
        for (int kk = 0; kk < 2; ++kk)
            qf[mt][kk] = *(const short8*)(qp + kk * 32 + quad * 8);
    }

    // ---- S = Q K^T, K fragments gathered from global (L2-hit)
    const unsigned short* Kbase = qkvb + KOFF + kh * DHEAD;
    floatx4 S[2][10];
    #pragma unroll
    for (int mt = 0; mt < 2; ++mt)
        #pragma unroll
        for (int nt = 0; nt < 10; ++nt) S[mt][nt] = (floatx4){0.f, 0.f, 0.f, 0.f};
    __builtin_amdgcn_s_setprio(1);
    #pragma unroll
    for (int kk = 0; kk < 2; ++kk) {
        #pragma unroll
        for (int nt = 0; nt < 10; ++nt) {
            int r = t0 - 127 + nt * 16 + ml;
            r = min(max(r, 0), NTOK - 1);
            short8 kb = *(const short8*)(Kbase + (size_t)r * QKV_N + kk * 32 + quad * 8);
            #pragma unroll
            for (int mt = 0; mt < 2; ++mt)
                S[mt][nt] = __builtin_amdgcn_mfma_f32_16x16x32_bf16(qf[mt][kk], kb, S[mt][nt], 0, 0, 0);
        }
    }
    __builtin_amdgcn_s_setprio(0);

    // ---- band mask + scale   (valid: w>=tl, w<=tl+127, w>=127-t0)
    int wmin0 = 127 - t0;
    #pragma unroll
    for (int mt = 0; mt < 2; ++mt) {
        #pragma unroll
        for (int r = 0; r < 4; ++r) {
            int tl = (wavebase + mt * 16 + quad * 4 + r) & 15;
            int wlo = tl > wmin0 ? tl : wmin0;
            int whi = tl + 127;
            #pragma unroll
            for (int nt = 0; nt < 10; ++nt) {
                int w = nt * 16 + ml;
                float s = S[mt][nt][r] * 0.125f;
                S[mt][nt][r] = (w >= wlo && w <= whi) ? s : -INFINITY;
            }
        }
    }

    // ---- softmax with sink (rows spread over 16 lanes of the quad)
    #pragma unroll
    for (int mt = 0; mt < 2; ++mt) {
        int g = (wavebase + mt * 16) >> 4;
        float sk = sinks[kh * GQ + g];
        #pragma unroll
        for (int r = 0; r < 4; ++r) {
            float rm = -INFINITY;
            #pragma unroll
            for (int nt = 0; nt < 10; ++nt) rm = fmaxf(rm, S[mt][nt][r]);
            #pragma unroll
            for (int off = 1; off < 16; off <<= 1) rm = fmaxf(rm, __shfl_xor(rm, off));
            rm = fmaxf(rm, sk);
            float sum = 0.f;
            #pragma unroll
            for (int nt = 0; nt < 10; ++nt) {
                float p = __expf(S[mt][nt][r] - rm);   // exp(-inf)=0 masks
                S[mt][nt][r] = p;
                sum += p;
            }
            #pragma unroll
            for (int off = 1; off < 16; off <<= 1) sum += __shfl_xor(sum, off);
            float inv = 1.f / (sum + __expf(sk - rm));
            #pragma unroll
            for (int nt = 0; nt < 10; ++nt) S[mt][nt][r] *= inv;
        }
    }

    // ---- PV one m-tile at a time through per-wave Ps (wave DS ops in-order)
    #pragma unroll
    for (int mt = 0; mt < 2; ++mt) {
        #pragma unroll
        for (int r = 0; r < 4; ++r) {
            int lr = quad * 4 + r;
            #pragma unroll
            for (int nt = 0; nt < 10; ++nt)
                Psw[lr * PS_LD + nt * 16 + ml] = f2b(S[mt][nt][r]);
        }
        floatx4 O[4];
        #pragma unroll
        for (int j = 0; j < 4; ++j) O[j] = (floatx4){0.f, 0.f, 0.f, 0.f};
        __builtin_amdgcn_s_setprio(1);
        #pragma unroll
        for (int ks = 0; ks < 5; ++ks) {
            short8 pf = *(const short8*)&Psw[ml * PS_LD + ks * 32 + quad * 8];
            #pragma unroll
            for (int nt = 0; nt < 4; ++nt) {
                int d = nt * 16 + ml;
                int u = ((ks * 4 + quad) ^ ((d >> 3) & 7)) << 3;   // swizzled unit
                short8 vf = *(const short8*)&Vt[d * VT_LD + u];
                O[nt] = __builtin_amdgcn_mfma_f32_16x16x32_bf16(pf, vf, O[nt], 0, 0, 0);
            }
        }
        __builtin_amdgcn_s_setprio(0);
        #pragma unroll
        for (int r = 0; r < 4; ++r) {
            int mm = wavebase + mt * 16 + quad * 4 + r;
            int tl = mm & 15, g = mm >> 4;
            unsigned short* op = aout + (size_t)(t0 + tl) * QCOLS + (kh * GQ + g) * DHEAD;
            #pragma unroll
            for (int nt = 0; nt < 4; ++nt)
                op[nt * 16 + ml] = f2b(O[nt][r]);
        }
    }
}

// ---------------------------------------------------------------------------
extern "C" void kernel_launch(void* const* d_in, const int* in_sizes, int n_in,
                              void* d_out, int out_size, void* d_ws, size_t ws_size,
                              hipStream_t stream) {
    const float* X     = (const float*)d_in[0];  // 1024x2880 f32
    const float* Wqkv  = (const float*)d_in[1];  // 2880x5120 f32
    const float* Wo    = (const float*)d_in[2];  // 4096x2880 f32
    const float* sinks = (const float*)d_in[3];  // 64 f32
    float* out = (float*)d_out;                  // 1024x2880 f32

    unsigned short *Xb, *qkvb, *attn, *WqkvT, *WoT;
    hipGetSymbolAddress((void**)&Xb,    HIP_SYMBOL(g_Xb));
    hipGetSymbolAddress((void**)&qkvb,  HIP_SYMBOL(g_qkvb));
    hipGetSymbolAddress((void**)&attn,  HIP_SYMBOL(g_attn));
    hipGetSymbolAddress((void**)&WqkvT, HIP_SYMBOL(g_WqkvT));
    hipGetSymbolAddress((void**)&WoT,   HIP_SYMBOL(g_WoT));

    // Wqkv transpose + X cvt (Wo transpose deferred into attn_fused)
    prep1<<<NB_WQKV + NB_CVT, 256, 0, stream>>>(X, Wqkv, Xb, WqkvT);

    // QKV projection, fused RoPE -> bf16 qkv (640 blocks)
    gemm_dir<HDIM, 0, QKV_N / 64><<<8 * (QKV_N / 64), 256, 0, stream>>>(Xb, WqkvT, qkvb);

    // attn (512 blocks) + concurrent Wo transpose (2880 blocks)
    attn_fused<<<ATTN_NB + NB_WO, 256, 0, stream>>>(qkvb, sinks, attn, Wo, WoT);

    // Output projection -> f32 out (360 blocks)
    gemm_dir<QCOLS, 1, HDIM / 64><<<8 * (HDIM / 64), 256, 0, stream>>>(attn, WoT, out);
}